// Round 1
// baseline (2504.661 us; speedup 1.0000x reference)
//
#include <hip/hip_runtime.h>
#include <math.h>

#define CH 128

// ============================ CSR build ============================

__global__ void count_kernel(const int* __restrict__ dst, int n, int* __restrict__ cnt) {
  int stride = gridDim.x * blockDim.x;
  for (int e = blockIdx.x * blockDim.x + threadIdx.x; e < n; e += stride)
    atomicAdd(&cnt[dst[e]], 1);
}

// single-block Hillis-Steele exclusive scan; n up to ~100001, writes off[0..n]
__global__ void exscan_kernel(const int* __restrict__ cnt, int n, int* __restrict__ off) {
  __shared__ int buf[1024];
  int running = 0;
  for (int base = 0; base < n; base += 1024) {
    int i = base + (int)threadIdx.x;
    int v = (i < n) ? cnt[i] : 0;
    buf[threadIdx.x] = v;
    __syncthreads();
    for (int d = 1; d < 1024; d <<= 1) {
      int t = (threadIdx.x >= (unsigned)d) ? buf[threadIdx.x - d] : 0;
      __syncthreads();
      buf[threadIdx.x] += t;
      __syncthreads();
    }
    if (i < n) off[i] = running + buf[threadIdx.x] - v;  // exclusive
    int total = buf[1023];
    __syncthreads();
    running += total;
  }
  if (threadIdx.x == 0) off[n] = running;
}

__global__ void fill_kernel(const int* __restrict__ dst, int n, const int* __restrict__ off,
                            int* __restrict__ cur, int* __restrict__ eids) {
  int stride = gridDim.x * blockDim.x;
  for (int e = blockIdx.x * blockDim.x + threadIdx.x; e < n; e += stride) {
    int d = dst[e];
    int p = off[d] + atomicAdd(&cur[d], 1);
    eids[p] = e;
  }
}

// ============================ output init ============================
// out layout: [user_res (NU*CH)] [entity_res (NE*CH)] [node_res (NN*CH)]
// both halves initialized to [user | entity]
__global__ void init_out_kernel(const float* __restrict__ user, const float* __restrict__ ent,
                                float* __restrict__ out, int nu4, int ne4) {
  int i = blockIdx.x * blockDim.x + threadIdx.x;
  int half = nu4 + ne4;
  if (i >= 2 * half) return;
  int k = (i >= half) ? i - half : i;
  float4 v = (k < nu4) ? ((const float4*)user)[k] : ((const float4*)ent)[k - nu4];
  ((float4*)out)[i] = v;
}

// ============================ Q/K projection ============================
// Out[row][c] = sum_k X[row][k] * W[k][c] ; X = concat(user, ent)
// block = 256 threads, 32 rows per block staged in LDS
__global__ __launch_bounds__(256) void qk_kernel(const float* __restrict__ user,
                                                 const float* __restrict__ ent,
                                                 const float* __restrict__ Wmat,
                                                 float* __restrict__ Out,
                                                 int n_users, int n_nodes) {
  __shared__ float X[32 * CH];
  const int t = threadIdx.x;
  const int row0 = blockIdx.x * 32;
  for (int i = t; i < 32 * 32; i += 256) {  // 32 rows x 32 float4
    int r = i >> 5, c4 = i & 31;
    int row = row0 + r;
    float4 v = make_float4(0.f, 0.f, 0.f, 0.f);
    if (row < n_nodes) {
      const float* src = (row < n_users) ? (user + (size_t)row * CH)
                                         : (ent + (size_t)(row - n_users) * CH);
      v = ((const float4*)src)[c4];
    }
    ((float4*)X)[i] = v;
  }
  __syncthreads();
  const int c = t & 127;
  const int rg = t >> 7;  // 0..1, 16 rows each
  float acc[16];
#pragma unroll
  for (int r = 0; r < 16; ++r) acc[r] = 0.f;
  for (int k4 = 0; k4 < CH; k4 += 4) {
    float w0 = Wmat[(k4 + 0) * CH + c];
    float w1 = Wmat[(k4 + 1) * CH + c];
    float w2 = Wmat[(k4 + 2) * CH + c];
    float w3 = Wmat[(k4 + 3) * CH + c];
#pragma unroll
    for (int r = 0; r < 16; ++r) {
      float4 x = *(const float4*)&X[(rg * 16 + r) * CH + k4];
      acc[r] += x.x * w0 + x.y * w1 + x.z * w2 + x.w * w3;
    }
  }
  for (int r = 0; r < 16; ++r) {
    int row = row0 + rg * 16 + r;
    if (row < n_nodes) Out[(size_t)row * CH + c] = acc[r];
  }
}

// ============================ per-edge attention scores ============================
// one wave per edge: score[e][h] = (Q[head] . K[tail])_head / 8
__global__ __launch_bounds__(256) void escore_kernel(const float* __restrict__ Q,
                                                     const float* __restrict__ K,
                                                     const int* __restrict__ eh,
                                                     const int* __restrict__ et,
                                                     float* __restrict__ scores, int n_edges) {
  int wid = (int)((blockIdx.x * 256 + threadIdx.x) >> 6);
  int lane = threadIdx.x & 63;
  if (wid >= n_edges) return;
  int h = eh[wid], tl = et[wid];
  const float* q = Q + (size_t)h * CH;
  const float* k = K + (size_t)tl * CH;
  float p0 = q[lane] * k[lane];
  float p1 = q[64 + lane] * k[64 + lane];
#pragma unroll
  for (int d = 32; d; d >>= 1) {
    p0 += __shfl_xor(p0, d);
    p1 += __shfl_xor(p1, d);
  }
  if (lane == 0) {
    scores[2 * (size_t)wid] = p0 * 0.125f;   // 1/sqrt(64)
    scores[2 * (size_t)wid + 1] = p1 * 0.125f;
  }
}

// ============================ scatter-softmax over head groups ============================
// one wave per node; 3 passes over that node's edges (avg deg ~10)
__global__ __launch_bounds__(256) void attn_kernel(const int* __restrict__ off,
                                                   const int* __restrict__ eids,
                                                   const float* __restrict__ scores,
                                                   float* __restrict__ aug_w, int n_nodes) {
  int wid = (int)((blockIdx.x * 256 + threadIdx.x) >> 6);
  int lane = threadIdx.x & 63;
  if (wid >= n_nodes) return;
  int o0 = off[wid], o1 = off[wid + 1];
  int deg = o1 - o0;
  if (deg == 0) return;
  float m0 = -3.4e38f, m1 = -3.4e38f;
  for (int i = lane; i < deg; i += 64) {
    int e = eids[o0 + i];
    m0 = fmaxf(m0, scores[2 * (size_t)e]);
    m1 = fmaxf(m1, scores[2 * (size_t)e + 1]);
  }
#pragma unroll
  for (int d = 32; d; d >>= 1) {
    m0 = fmaxf(m0, __shfl_xor(m0, d));
    m1 = fmaxf(m1, __shfl_xor(m1, d));
  }
  float z0 = 0.f, z1 = 0.f;
  for (int i = lane; i < deg; i += 64) {
    int e = eids[o0 + i];
    z0 += expf(scores[2 * (size_t)e] - m0);
    z1 += expf(scores[2 * (size_t)e + 1] - m1);
  }
#pragma unroll
  for (int d = 32; d; d >>= 1) {
    z0 += __shfl_xor(z0, d);
    z1 += __shfl_xor(z1, d);
  }
  float iz0 = 1.f / z0, iz1 = 1.f / z1;
  for (int i = lane; i < deg; i += 64) {
    int e = eids[o0 + i];
    float a0 = expf(scores[2 * (size_t)e] - m0) * iz0;
    float a1 = expf(scores[2 * (size_t)e + 1] - m1) * iz1;
    aug_w[e] = 0.5f * (a0 + a1);
  }
}

// ============================ hop kernels (block = 1 row, 128 threads) ============================

// entity KG aggregation: mean over edges of src[tail]*weight[rel], then l2norm,
// writes un-normalized (Eun) for the interact step, normalized (En) for next hop,
// and accumulates normalized into entity residual.
__global__ __launch_bounds__(128) void entity_agg_kernel(
    const float* __restrict__ src, const int* __restrict__ kg_tail,
    const int* __restrict__ etype, const float* __restrict__ weight,
    const int* __restrict__ off, const int* __restrict__ eids,
    float* __restrict__ Eun, float* __restrict__ En, float* __restrict__ res_ent,
    int write_norm) {
  int n = blockIdx.x;
  int c = threadIdx.x;
  int o0 = off[n], o1 = off[n + 1];
  float acc = 0.f;
  for (int i = o0; i < o1; ++i) {
    int e = eids[i];
    int tl = kg_tail[e];
    int r = etype[e] - 1;
    acc += src[(size_t)tl * CH + c] * weight[r * CH + c];
  }
  int deg = o1 - o0;
  float mean = acc / (float)(deg > 0 ? deg : 1);
  Eun[(size_t)n * CH + c] = mean;
  float ss = mean * mean;
#pragma unroll
  for (int d = 32; d; d >>= 1) ss += __shfl_xor(ss, d);
  __shared__ float red[2];
  if ((threadIdx.x & 63) == 0) red[threadIdx.x >> 6] = ss;
  __syncthreads();
  float tot = red[0] + red[1];
  float scale = 1.f / fmaxf(sqrtf(tot), 1e-12f);
  float nv = mean * scale;
  if (write_norm) En[(size_t)n * CH + c] = nv;
  res_ent[(size_t)n * CH + c] += nv;
}

// preference-graph aggregation with attention edge weights
__global__ __launch_bounds__(128) void node_agg_kernel(
    const float* __restrict__ srcU, const float* __restrict__ srcE,
    const int* __restrict__ ex_tail, const float* __restrict__ aug_w,
    const int* __restrict__ off, const int* __restrict__ eids,
    float* __restrict__ Nn, float* __restrict__ res_node, int write_norm, int n_users) {
  int n = blockIdx.x;
  int c = threadIdx.x;
  int o0 = off[n], o1 = off[n + 1];
  float acc = 0.f;
  for (int i = o0; i < o1; ++i) {
    int e = eids[i];
    int tl = ex_tail[e];
    float w = aug_w[e];
    const float* s = (tl < n_users) ? (srcU + (size_t)tl * CH)
                                    : (srcE + (size_t)(tl - n_users) * CH);
    acc += s[c] * w;
  }
  int deg = o1 - o0;
  float mean = acc / (float)(deg > 0 ? deg : 1);
  float ss = mean * mean;
#pragma unroll
  for (int d = 32; d; d >>= 1) ss += __shfl_xor(ss, d);
  __shared__ float red[2];
  if ((threadIdx.x & 63) == 0) red[threadIdx.x >> 6] = ss;
  __syncthreads();
  float tot = red[0] + red[1];
  float scale = 1.f / fmaxf(sqrtf(tot), 1e-12f);
  float nv = mean * scale;
  if (write_norm) Nn[(size_t)n * CH + c] = nv;
  res_node[(size_t)n * CH + c] += nv;
}

// user = segment_sum(vals * Eun[cols]) over interact CSR, then l2norm, accumulate residual
__global__ __launch_bounds__(128) void user_agg_kernel(
    const float* __restrict__ Eun, const int* __restrict__ it_cols,
    const float* __restrict__ it_vals, const int* __restrict__ off,
    const int* __restrict__ eids, float* __restrict__ res_user) {
  int u = blockIdx.x;
  int c = threadIdx.x;
  int o0 = off[u], o1 = off[u + 1];
  float acc = 0.f;
  for (int i = o0; i < o1; ++i) {
    int e = eids[i];
    acc += it_vals[e] * Eun[(size_t)it_cols[e] * CH + c];
  }
  float ss = acc * acc;
#pragma unroll
  for (int d = 32; d; d >>= 1) ss += __shfl_xor(ss, d);
  __shared__ float red[2];
  if ((threadIdx.x & 63) == 0) red[threadIdx.x >> 6] = ss;
  __syncthreads();
  float tot = red[0] + red[1];
  float scale = 1.f / fmaxf(sqrtf(tot), 1e-12f);
  res_user[(size_t)u * CH + c] += acc * scale;
}

// ============================ host ============================

extern "C" void kernel_launch(void* const* d_in, const int* in_sizes, int n_in,
                              void* d_out, int out_size, void* d_ws, size_t ws_size,
                              hipStream_t stream) {
  const float* user_emb = (const float*)d_in[0];
  const float* ent_emb  = (const float*)d_in[1];
  const int*   edge_index = (const int*)d_in[2];
  const int*   edge_type  = (const int*)d_in[3];
  const int*   ex_index   = (const int*)d_in[4];
  const int*   it_rows = (const int*)d_in[6];
  const int*   it_cols = (const int*)d_in[7];
  const float* it_vals = (const float*)d_in[8];
  const float* weight  = (const float*)d_in[9];
  const float* W_Q = (const float*)d_in[11];
  const float* W_K = (const float*)d_in[12];

  const int n_users = in_sizes[0] / CH;
  const int n_ents  = in_sizes[1] / CH;
  const int n_nodes = n_users + n_ents;
  const int n_kg    = in_sizes[3];       // KG edges
  const int n_ex    = in_sizes[5];       // extra (preference) edges
  const int nnz     = in_sizes[8];       // interactions

  const int* kg_head = edge_index;
  const int* kg_tail = edge_index + n_kg;
  const int* ex_head = ex_index;
  const int* ex_tail = ex_index + n_ex;

  // ---- workspace bump allocator (256B aligned) ----
  char* p = (char*)d_ws;
  auto alloc = [&](size_t bytes) -> char* {
    char* r = p;
    p += (bytes + 255) & ~(size_t)255;
    return r;
  };
  int* eids_kg = (int*)alloc((size_t)n_kg * 4);
  int* eids_ex = (int*)alloc((size_t)n_ex * 4);
  int* eids_it = (int*)alloc((size_t)nnz * 4);
  char* cnt_base = alloc((size_t)(n_ents + n_nodes + n_users) * 4);
  int* cnt_kg = (int*)cnt_base;
  int* cnt_ex = cnt_kg + n_ents;
  int* cnt_it = cnt_ex + n_nodes;
  size_t cnt_bytes = (size_t)(n_ents + n_nodes + n_users) * 4;
  int* off_kg = (int*)alloc((size_t)(n_ents + 1) * 4);
  int* off_ex = (int*)alloc((size_t)(n_nodes + 1) * 4);
  int* off_it = (int*)alloc((size_t)(n_users + 1) * 4);
  float* scores = (float*)alloc((size_t)n_ex * 2 * 4);
  float* aug_w  = (float*)alloc((size_t)n_ex * 4);
  // big region: phase A = Q,K tables; phase B = Eun/En0/Nn0 (Q,K dead by then)
  size_t bigA = (size_t)2 * n_nodes * CH;
  size_t bigB = (size_t)2 * n_ents * CH + (size_t)n_nodes * CH;
  float* big = (float*)alloc((bigA > bigB ? bigA : bigB) * 4);
  float* Qt = big;
  float* Kt = big + (size_t)n_nodes * CH;
  float* Eun = big;
  float* En0 = big + (size_t)n_ents * CH;
  float* Nn0 = big + (size_t)2 * n_ents * CH;

  float* res_user = (float*)d_out;                              // [n_users][CH]
  float* res_ent  = (float*)d_out + (size_t)n_users * CH;       // [n_ents][CH]
  float* res_node = (float*)d_out + (size_t)n_nodes * CH;       // [n_nodes][CH]

  // ---- 1. CSR build for the three graphs ----
  hipMemsetAsync(cnt_base, 0, cnt_bytes, stream);
  count_kernel<<<2048, 256, 0, stream>>>(kg_head, n_kg, cnt_kg);
  count_kernel<<<2048, 256, 0, stream>>>(ex_head, n_ex, cnt_ex);
  count_kernel<<<2048, 256, 0, stream>>>(it_rows, nnz, cnt_it);
  exscan_kernel<<<1, 1024, 0, stream>>>(cnt_kg, n_ents, off_kg);
  exscan_kernel<<<1, 1024, 0, stream>>>(cnt_ex, n_nodes, off_ex);
  exscan_kernel<<<1, 1024, 0, stream>>>(cnt_it, n_users, off_it);
  hipMemsetAsync(cnt_base, 0, cnt_bytes, stream);
  fill_kernel<<<2048, 256, 0, stream>>>(kg_head, n_kg, off_kg, cnt_kg, eids_kg);
  fill_kernel<<<2048, 256, 0, stream>>>(ex_head, n_ex, off_ex, cnt_ex, eids_ex);
  fill_kernel<<<2048, 256, 0, stream>>>(it_rows, nnz, off_it, cnt_it, eids_it);

  // ---- 2. residual init: d_out = [user|ent|user|ent] ----
  {
    int nu4 = n_users * (CH / 4), ne4 = n_ents * (CH / 4);
    int total = 2 * (nu4 + ne4);
    init_out_kernel<<<(total + 255) / 256, 256, 0, stream>>>(user_emb, ent_emb,
                                                             (float*)d_out, nu4, ne4);
  }

  // ---- 3. attention edge weights (once, on raw concat embeddings) ----
  {
    int blocks = (n_nodes + 31) / 32;
    qk_kernel<<<blocks, 256, 0, stream>>>(user_emb, ent_emb, W_Q, Qt, n_users, n_nodes);
    qk_kernel<<<blocks, 256, 0, stream>>>(user_emb, ent_emb, W_K, Kt, n_users, n_nodes);
  }
  escore_kernel<<<(n_ex * 64 + 255) / 256, 256, 0, stream>>>(Qt, Kt, ex_head, ex_tail,
                                                             scores, n_ex);
  attn_kernel<<<(n_nodes * 64 + 255) / 256, 256, 0, stream>>>(off_ex, eids_ex, scores,
                                                              aug_w, n_nodes);

  // ---- 4. hop 1 ----
  entity_agg_kernel<<<n_ents, 128, 0, stream>>>(ent_emb, kg_tail, edge_type, weight,
                                                off_kg, eids_kg, Eun, En0, res_ent, 1);
  node_agg_kernel<<<n_nodes, 128, 0, stream>>>(user_emb, ent_emb, ex_tail, aug_w,
                                               off_ex, eids_ex, Nn0, res_node, 1, n_users);
  user_agg_kernel<<<n_users, 128, 0, stream>>>(Eun, it_cols, it_vals, off_it, eids_it,
                                               res_user);

  // ---- 5. hop 2 (normalized buffers from hop 1 as sources; no next-state writes) ----
  entity_agg_kernel<<<n_ents, 128, 0, stream>>>(En0, kg_tail, edge_type, weight,
                                                off_kg, eids_kg, Eun, En0, res_ent, 0);
  node_agg_kernel<<<n_nodes, 128, 0, stream>>>(Nn0, Nn0 + (size_t)n_users * CH, ex_tail,
                                               aug_w, off_ex, eids_ex, Nn0, res_node, 0,
                                               n_users);
  user_agg_kernel<<<n_users, 128, 0, stream>>>(Eun, it_cols, it_vals, off_it, eids_it,
                                               res_user);
}

// Round 4
// 1509.143 us; speedup vs baseline: 1.6597x; 1.6597x over previous
//
#include <hip/hip_runtime.h>
#include <math.h>

#define CH 128

// ---------- bf16 helpers (bf16 = top 16 bits of f32, RTN encode) ----------
__device__ __forceinline__ unsigned int bf16enc1(float f) {
  unsigned int b = __float_as_uint(f);
  return (b + 0x7fffu + ((b >> 16) & 1u)) >> 16;
}
__device__ __forceinline__ unsigned int bf16pack2(float lo, float hi) {
  return bf16enc1(lo) | (bf16enc1(hi) << 16);
}
__device__ __forceinline__ float bf16lo(unsigned int u) { return __uint_as_float(u << 16); }
__device__ __forceinline__ float bf16hi(unsigned int u) { return __uint_as_float(u & 0xffff0000u); }

// ============================ CSR build ============================

__global__ void count_kernel(const int* __restrict__ dst, int n, int* __restrict__ cnt) {
  int stride = gridDim.x * blockDim.x;
  for (int e = blockIdx.x * blockDim.x + threadIdx.x; e < n; e += stride)
    atomicAdd(&cnt[dst[e]], 1);
}

// single-block exclusive scan, shuffle-based (2-3 barriers per 1024-tile)
__global__ __launch_bounds__(1024) void exscan_kernel(const int* __restrict__ cnt, int n,
                                                      int* __restrict__ off) {
  __shared__ int wsum[16];
  int lane = threadIdx.x & 63;
  int wid = threadIdx.x >> 6;
  int running = 0;
  for (int base = 0; base < n; base += 1024) {
    int i = base + (int)threadIdx.x;
    int v = (i < n) ? cnt[i] : 0;
    int x = v;
#pragma unroll
    for (int d = 1; d < 64; d <<= 1) {
      int t = __shfl_up(x, d);
      if (lane >= d) x += t;
    }
    if (lane == 63) wsum[wid] = x;
    __syncthreads();
    if (wid == 0) {
      int y = (lane < 16) ? wsum[lane] : 0;
#pragma unroll
      for (int d = 1; d < 16; d <<= 1) {
        int t = __shfl_up(y, d);
        if (lane >= d) y += t;
      }
      if (lane < 16) wsum[lane] = y;
    }
    __syncthreads();
    int wbase = wid ? wsum[wid - 1] : 0;
    if (i < n) off[i] = running + wbase + x - v;  // exclusive
    running += wsum[15];
    __syncthreads();  // wsum reused next tile
  }
  if (threadIdx.x == 0) off[n] = running;
}

// fill variants: scatter the per-edge payload into its CSR slot
__global__ void fill_kg_kernel(const int* __restrict__ head, const int* __restrict__ tail,
                               const int* __restrict__ type, int n,
                               const int* __restrict__ off, int* __restrict__ cur,
                               int2* __restrict__ pay) {
  int stride = gridDim.x * blockDim.x;
  for (int e = blockIdx.x * blockDim.x + threadIdx.x; e < n; e += stride) {
    int d = head[e];
    int p = off[d] + atomicAdd(&cur[d], 1);
    pay[p] = make_int2(tail[e], type[e] - 1);
  }
}

__global__ void fill_ex_kernel(const int* __restrict__ head, const int* __restrict__ tail,
                               int n, const int* __restrict__ off, int* __restrict__ cur,
                               int* __restrict__ pay /*int2 view*/, int* __restrict__ slot) {
  int stride = gridDim.x * blockDim.x;
  for (int e = blockIdx.x * blockDim.x + threadIdx.x; e < n; e += stride) {
    int d = head[e];
    int p = off[d] + atomicAdd(&cur[d], 1);
    pay[2 * (size_t)p] = tail[e];  // .y (aug weight) written later by attn
    slot[e] = p;
  }
}

__global__ void fill_it_kernel(const int* __restrict__ rows, const int* __restrict__ cols,
                               const float* __restrict__ vals, int n,
                               const int* __restrict__ off, int* __restrict__ cur,
                               int2* __restrict__ pay) {
  int stride = gridDim.x * blockDim.x;
  for (int e = blockIdx.x * blockDim.x + threadIdx.x; e < n; e += stride) {
    int d = rows[e];
    int p = off[d] + atomicAdd(&cur[d], 1);
    pay[p] = make_int2(cols[e], __float_as_int(vals[e]));
  }
}

// ============================ output init ============================
// out layout: [user_res][entity_res][node_res]; both halves start as [user|ent]
__global__ void init_out_kernel(const float* __restrict__ user, const float* __restrict__ ent,
                                float* __restrict__ out, int nu4, int ne4) {
  int i = blockIdx.x * blockDim.x + threadIdx.x;
  int half = nu4 + ne4;
  if (i >= 2 * half) return;
  int k = (i >= half) ? i - half : i;
  float4 v = (k < nu4) ? ((const float4*)user)[k] : ((const float4*)ent)[k - nu4];
  ((float4*)out)[i] = v;
}

// ============================ Q/K projection (fp32 in, bf16 out) ============================
__global__ __launch_bounds__(256) void qk_kernel(const float* __restrict__ user,
                                                 const float* __restrict__ ent,
                                                 const float* __restrict__ Wmat,
                                                 unsigned short* __restrict__ Out,
                                                 int n_users, int n_nodes) {
  __shared__ float X[32 * CH];
  const int t = threadIdx.x;
  const int row0 = blockIdx.x * 32;
  for (int i = t; i < 32 * 32; i += 256) {
    int r = i >> 5, c4 = i & 31;
    int row = row0 + r;
    float4 v = make_float4(0.f, 0.f, 0.f, 0.f);
    if (row < n_nodes) {
      const float* src = (row < n_users) ? (user + (size_t)row * CH)
                                         : (ent + (size_t)(row - n_users) * CH);
      v = ((const float4*)src)[c4];
    }
    ((float4*)X)[i] = v;
  }
  __syncthreads();
  const int c = t & 127;
  const int rg = t >> 7;
  float acc[16];
#pragma unroll
  for (int r = 0; r < 16; ++r) acc[r] = 0.f;
  for (int k4 = 0; k4 < CH; k4 += 4) {
    float w0 = Wmat[(k4 + 0) * CH + c];
    float w1 = Wmat[(k4 + 1) * CH + c];
    float w2 = Wmat[(k4 + 2) * CH + c];
    float w3 = Wmat[(k4 + 3) * CH + c];
#pragma unroll
    for (int r = 0; r < 16; ++r) {
      float4 x = *(const float4*)&X[(rg * 16 + r) * CH + k4];
      acc[r] += x.x * w0 + x.y * w1 + x.z * w2 + x.w * w3;
    }
  }
  for (int r = 0; r < 16; ++r) {
    int row = row0 + rg * 16 + r;
    if (row < n_nodes) Out[(size_t)row * CH + c] = (unsigned short)bf16enc1(acc[r]);
  }
}

// ============================ per-edge attention scores ============================
// wave per edge; bf16 Q/K rows (256 B each); scores scattered PRE-SORTED via slot[]
__global__ __launch_bounds__(256) void escore_kernel(const unsigned int* __restrict__ Q,
                                                     const unsigned int* __restrict__ K,
                                                     const int* __restrict__ eh,
                                                     const int* __restrict__ et,
                                                     const int* __restrict__ slot,
                                                     float2* __restrict__ scores, int n_edges) {
  int wid = (int)((blockIdx.x * 256 + threadIdx.x) >> 6);
  int lane = threadIdx.x & 63;
  if (wid >= n_edges) return;
  int h = eh[wid], tl = et[wid];
  unsigned int qu = Q[(size_t)h * 64 + lane];
  unsigned int ku = K[(size_t)tl * 64 + lane];
  float p = bf16lo(qu) * bf16lo(ku) + bf16hi(qu) * bf16hi(ku);
#pragma unroll
  for (int d = 16; d; d >>= 1) p += __shfl_xor(p, d);  // reduce within 32-lane halves
  float p1 = __shfl(p, 32);                            // head1 total (lanes 32-63 cover ch 64-127)
  if (lane == 0) scores[slot[wid]] = make_float2(p * 0.125f, p1 * 0.125f);
}

// ============================ scatter-softmax (contiguous per node) ============================
__global__ __launch_bounds__(256) void attn_kernel(const int* __restrict__ off,
                                                   const float2* __restrict__ scores,
                                                   int* __restrict__ pay_ex /*int2 view*/,
                                                   int n_nodes) {
  int wid = (int)((blockIdx.x * 256 + threadIdx.x) >> 6);
  int lane = threadIdx.x & 63;
  if (wid >= n_nodes) return;
  int o0 = off[wid], o1 = off[wid + 1];
  int deg = o1 - o0;
  if (deg == 0) return;
  float m0 = -3.4e38f, m1 = -3.4e38f;
  for (int i = lane; i < deg; i += 64) {
    float2 s = scores[o0 + i];
    m0 = fmaxf(m0, s.x);
    m1 = fmaxf(m1, s.y);
  }
#pragma unroll
  for (int d = 32; d; d >>= 1) {
    m0 = fmaxf(m0, __shfl_xor(m0, d));
    m1 = fmaxf(m1, __shfl_xor(m1, d));
  }
  float z0 = 0.f, z1 = 0.f;
  for (int i = lane; i < deg; i += 64) {
    float2 s = scores[o0 + i];
    z0 += expf(s.x - m0);
    z1 += expf(s.y - m1);
  }
#pragma unroll
  for (int d = 32; d; d >>= 1) {
    z0 += __shfl_xor(z0, d);
    z1 += __shfl_xor(z1, d);
  }
  float iz0 = 1.f / z0, iz1 = 1.f / z1;
  for (int i = lane; i < deg; i += 64) {
    float2 s = scores[o0 + i];
    float a = 0.5f * (expf(s.x - m0) * iz0 + expf(s.y - m1) * iz1);
    pay_ex[2 * (size_t)(o0 + i) + 1] = __float_as_int(a);
  }
}

// ============================ aggregation kernels (wave per row) ============================

// entity KG agg: acc over edges of src[tail]*(rscale)*weight[rel]; mean; l2norm
// NOTE: rscale_out is written ONLY when HOP2==0. In hop 2 rscale_in aliases the
// hop-1 rscale buffer that concurrent waves are still reading — writing it was
// the round-3 correctness race.
template <int HOP2>
__global__ __launch_bounds__(256) void entity_agg_kernel(
    const float* __restrict__ src, const int2* __restrict__ pay,
    const float* __restrict__ weight, const int* __restrict__ off,
    const float* __restrict__ rscale_in, float* __restrict__ Eout,
    float* __restrict__ rscale_out, float* __restrict__ res, int n) {
  int w = (int)((blockIdx.x * 256 + threadIdx.x) >> 6);
  int lane = threadIdx.x & 63;
  if (w >= n) return;
  int o0 = off[w], o1 = off[w + 1];
  float ax = 0.f, ay = 0.f;
#define EBODY(I)                                                      \
  {                                                                   \
    int2 pr = pay[I];                                                 \
    float rs = HOP2 ? rscale_in[pr.x] : 1.f;                          \
    float2 sv = ((const float2*)(src + (size_t)pr.x * CH))[lane];     \
    float2 wv = ((const float2*)(weight + (size_t)pr.y * CH))[lane];  \
    ax += sv.x * wv.x * rs;                                           \
    ay += sv.y * wv.y * rs;                                           \
  }
  int i = o0;
  for (; i + 4 <= o1; i += 4) { EBODY(i) EBODY(i + 1) EBODY(i + 2) EBODY(i + 3) }
  for (; i < o1; ++i) EBODY(i)
#undef EBODY
  int deg = o1 - o0;
  float inv = 1.f / (float)(deg > 0 ? deg : 1);
  ax *= inv;
  ay *= inv;
  float ss = ax * ax + ay * ay;
#pragma unroll
  for (int d = 32; d; d >>= 1) ss += __shfl_xor(ss, d);
  float scale = 1.f / fmaxf(sqrtf(ss), 1e-12f);
  ((float2*)(Eout + (size_t)w * CH))[lane] = make_float2(ax, ay);
  if (!HOP2 && lane == 0) rscale_out[w] = scale;   // race fix: no write in hop 2
  float2* rp = (float2*)(res + (size_t)w * CH);
  float2 r = rp[lane];
  r.x += ax * scale;
  r.y += ay * scale;
  rp[lane] = r;
}

// preference-graph agg; BF=1 → bf16 source (hop2), BF=0 → fp32 user/ent (hop1)
template <int BF>
__global__ __launch_bounds__(256) void node_agg_kernel(
    const void* __restrict__ srcU, const void* __restrict__ srcE,
    const int2* __restrict__ pay, const int* __restrict__ off,
    unsigned int* __restrict__ Nout /*bf16x2, may be unused*/,
    float* __restrict__ res, int n, int n_users, int write_norm) {
  int w = (int)((blockIdx.x * 256 + threadIdx.x) >> 6);
  int lane = threadIdx.x & 63;
  if (w >= n) return;
  int o0 = off[w], o1 = off[w + 1];
  float ax = 0.f, ay = 0.f;
#define NBODY(I)                                                          \
  {                                                                       \
    int2 pr = pay[I];                                                     \
    float aw = __int_as_float(pr.y);                                      \
    int tl = pr.x;                                                        \
    int r_ = (tl < n_users) ? tl : tl - n_users;                          \
    float sx, sy;                                                         \
    if (BF) {                                                             \
      const unsigned int* b =                                             \
          (const unsigned int*)((tl < n_users) ? srcU : srcE);            \
      unsigned int u = b[(size_t)r_ * 64 + lane];                         \
      sx = bf16lo(u);                                                     \
      sy = bf16hi(u);                                                     \
    } else {                                                              \
      const float* b = (const float*)((tl < n_users) ? srcU : srcE);      \
      float2 sv = ((const float2*)(b + (size_t)r_ * CH))[lane];           \
      sx = sv.x;                                                          \
      sy = sv.y;                                                          \
    }                                                                     \
    ax += sx * aw;                                                        \
    ay += sy * aw;                                                        \
  }
  int i = o0;
  for (; i + 4 <= o1; i += 4) { NBODY(i) NBODY(i + 1) NBODY(i + 2) NBODY(i + 3) }
  for (; i < o1; ++i) NBODY(i)
#undef NBODY
  int deg = o1 - o0;
  float inv = 1.f / (float)(deg > 0 ? deg : 1);
  ax *= inv;
  ay *= inv;
  float ss = ax * ax + ay * ay;
#pragma unroll
  for (int d = 32; d; d >>= 1) ss += __shfl_xor(ss, d);
  float scale = 1.f / fmaxf(sqrtf(ss), 1e-12f);
  float nx = ax * scale, ny = ay * scale;
  if (write_norm) Nout[(size_t)w * 64 + lane] = bf16pack2(nx, ny);
  float2* rp = (float2*)(res + (size_t)w * CH);
  float2 r = rp[lane];
  r.x += nx;
  r.y += ny;
  rp[lane] = r;
}

// user = segment_sum(val * Eun[col]); l2norm; accumulate residual
__global__ __launch_bounds__(256) void user_agg_kernel(const float* __restrict__ Eun,
                                                       const int2* __restrict__ pay,
                                                       const int* __restrict__ off,
                                                       float* __restrict__ res, int n) {
  int w = (int)((blockIdx.x * 256 + threadIdx.x) >> 6);
  int lane = threadIdx.x & 63;
  if (w >= n) return;
  int o0 = off[w], o1 = off[w + 1];
  float ax = 0.f, ay = 0.f;
#define UBODY(I)                                                    \
  {                                                                 \
    int2 pr = pay[I];                                               \
    float v = __int_as_float(pr.y);                                 \
    float2 sv = ((const float2*)(Eun + (size_t)pr.x * CH))[lane];   \
    ax += sv.x * v;                                                 \
    ay += sv.y * v;                                                 \
  }
  int i = o0;
  for (; i + 4 <= o1; i += 4) { UBODY(i) UBODY(i + 1) UBODY(i + 2) UBODY(i + 3) }
  for (; i < o1; ++i) UBODY(i)
#undef UBODY
  float ss = ax * ax + ay * ay;
#pragma unroll
  for (int d = 32; d; d >>= 1) ss += __shfl_xor(ss, d);
  float scale = 1.f / fmaxf(sqrtf(ss), 1e-12f);
  float2* rp = (float2*)(res + (size_t)w * CH);
  float2 r = rp[lane];
  r.x += ax * scale;
  r.y += ay * scale;
  rp[lane] = r;
}

// ============================ host ============================

extern "C" void kernel_launch(void* const* d_in, const int* in_sizes, int n_in,
                              void* d_out, int out_size, void* d_ws, size_t ws_size,
                              hipStream_t stream) {
  const float* user_emb = (const float*)d_in[0];
  const float* ent_emb  = (const float*)d_in[1];
  const int*   edge_index = (const int*)d_in[2];
  const int*   edge_type  = (const int*)d_in[3];
  const int*   ex_index   = (const int*)d_in[4];
  const int*   it_rows = (const int*)d_in[6];
  const int*   it_cols = (const int*)d_in[7];
  const float* it_vals = (const float*)d_in[8];
  const float* weight  = (const float*)d_in[9];
  const float* W_Q = (const float*)d_in[11];
  const float* W_K = (const float*)d_in[12];

  const int n_users = in_sizes[0] / CH;
  const int n_ents  = in_sizes[1] / CH;
  const int n_nodes = n_users + n_ents;
  const int n_kg    = in_sizes[3];
  const int n_ex    = in_sizes[5];
  const int nnz     = in_sizes[8];

  const int* kg_head = edge_index;
  const int* kg_tail = edge_index + n_kg;
  const int* ex_head = ex_index;
  const int* ex_tail = ex_index + n_ex;

  // ---- workspace bump allocator (256B aligned) ----
  char* p = (char*)d_ws;
  auto alloc = [&](size_t bytes) -> char* {
    char* r = p;
    p += (bytes + 255) & ~(size_t)255;
    return r;
  };
  int2* pay_kg = (int2*)alloc((size_t)n_kg * 8);
  int2* pay_ex = (int2*)alloc((size_t)n_ex * 8);
  // union: phase A = slot_ex + scores ; phase B = pay_it (fill deferred past attn)
  size_t slotb = ((size_t)n_ex * 4 + 255) & ~(size_t)255;
  size_t unionA = slotb + (size_t)n_ex * 8;
  size_t unionB = (size_t)nnz * 8;
  char* uA = alloc(unionA > unionB ? unionA : unionB);
  int*    slot_ex = (int*)uA;
  float2* scores  = (float2*)(uA + slotb);
  int2*   pay_it  = (int2*)uA;
  char* cnt_base = alloc((size_t)(n_ents + n_nodes + n_users) * 4);
  int* cnt_kg = (int*)cnt_base;
  int* cnt_ex = cnt_kg + n_ents;
  int* cnt_it = cnt_ex + n_nodes;
  size_t cnt_bytes = (size_t)(n_ents + n_nodes + n_users) * 4;
  int* off_kg = (int*)alloc((size_t)(n_ents + 1) * 4);
  int* off_ex = (int*)alloc((size_t)(n_nodes + 1) * 4);
  int* off_it = (int*)alloc((size_t)(n_users + 1) * 4);
  // arena: phase A = Qbf,Kbf (bf16) ; phase B = EunA,EunB (f32) + rscale + Nn (bf16)
  size_t arenaA = (size_t)2 * n_nodes * CH * 2;
  size_t arenaB = (size_t)2 * n_ents * CH * 4 + (size_t)n_ents * 4 + 256 +
                  (size_t)n_nodes * CH * 2;
  char* arena = alloc(arenaA > arenaB ? arenaA : arenaB);
  unsigned int* Qbf = (unsigned int*)arena;                       // [n_nodes][64] uint
  unsigned int* Kbf = Qbf + (size_t)n_nodes * 64;
  float* EunA = (float*)arena;
  float* EunB = EunA + (size_t)n_ents * CH;
  float* rscaleE = EunB + (size_t)n_ents * CH;
  unsigned int* Nnbf = (unsigned int*)(((uintptr_t)(rscaleE + n_ents) + 255) & ~(uintptr_t)255);

  float* res_user = (float*)d_out;
  float* res_ent  = (float*)d_out + (size_t)n_users * CH;
  float* res_node = (float*)d_out + (size_t)n_nodes * CH;

  // ---- 1. CSR counts + scans ----
  hipMemsetAsync(cnt_base, 0, cnt_bytes, stream);
  count_kernel<<<2048, 256, 0, stream>>>(kg_head, n_kg, cnt_kg);
  count_kernel<<<2048, 256, 0, stream>>>(ex_head, n_ex, cnt_ex);
  count_kernel<<<2048, 256, 0, stream>>>(it_rows, nnz, cnt_it);
  exscan_kernel<<<1, 1024, 0, stream>>>(cnt_kg, n_ents, off_kg);
  exscan_kernel<<<1, 1024, 0, stream>>>(cnt_ex, n_nodes, off_ex);
  exscan_kernel<<<1, 1024, 0, stream>>>(cnt_it, n_users, off_it);
  hipMemsetAsync(cnt_base, 0, cnt_bytes, stream);
  fill_kg_kernel<<<2048, 256, 0, stream>>>(kg_head, kg_tail, edge_type, n_kg, off_kg,
                                           cnt_kg, pay_kg);
  fill_ex_kernel<<<2048, 256, 0, stream>>>(ex_head, ex_tail, n_ex, off_ex, cnt_ex,
                                           (int*)pay_ex, slot_ex);

  // ---- 2. residual init ----
  {
    int nu4 = n_users * (CH / 4), ne4 = n_ents * (CH / 4);
    int total = 2 * (nu4 + ne4);
    init_out_kernel<<<(total + 255) / 256, 256, 0, stream>>>(user_emb, ent_emb,
                                                             (float*)d_out, nu4, ne4);
  }

  // ---- 3. attention (phase A of arena: Q/K bf16) ----
  {
    int blocks = (n_nodes + 31) / 32;
    qk_kernel<<<blocks, 256, 0, stream>>>(user_emb, ent_emb, W_Q, (unsigned short*)Qbf,
                                          n_users, n_nodes);
    qk_kernel<<<blocks, 256, 0, stream>>>(user_emb, ent_emb, W_K, (unsigned short*)Kbf,
                                          n_users, n_nodes);
  }
  escore_kernel<<<(n_ex + 3) / 4, 256, 0, stream>>>(Qbf, Kbf, ex_head, ex_tail, slot_ex,
                                                    scores, n_ex);
  attn_kernel<<<(n_nodes + 3) / 4, 256, 0, stream>>>(off_ex, scores, (int*)pay_ex, n_nodes);

  // ---- 4. interact CSR fill (overlaps dead slot/scores region) ----
  fill_it_kernel<<<2048, 256, 0, stream>>>(it_rows, it_cols, it_vals, nnz, off_it, cnt_it,
                                           pay_it);

  // ---- 5. hop 1 ----
  entity_agg_kernel<0><<<(n_ents + 3) / 4, 256, 0, stream>>>(
      ent_emb, pay_kg, weight, off_kg, nullptr, EunA, rscaleE, res_ent, n_ents);
  node_agg_kernel<0><<<(n_nodes + 3) / 4, 256, 0, stream>>>(
      user_emb, ent_emb, pay_ex, off_ex, Nnbf, res_node, n_nodes, n_users, 1);
  user_agg_kernel<<<(n_users + 3) / 4, 256, 0, stream>>>(EunA, pay_it, off_it, res_user,
                                                         n_users);

  // ---- 6. hop 2 ----
  entity_agg_kernel<1><<<(n_ents + 3) / 4, 256, 0, stream>>>(
      EunA, pay_kg, weight, off_kg, rscaleE, EunB, nullptr, res_ent, n_ents);
  node_agg_kernel<1><<<(n_nodes + 3) / 4, 256, 0, stream>>>(
      Nnbf, Nnbf + (size_t)n_users * 64, pay_ex, off_ex, Nnbf, res_node, n_nodes,
      n_users, 0);
  user_agg_kernel<<<(n_users + 3) / 4, 256, 0, stream>>>(EunB, pay_it, off_it, res_user,
                                                         n_users);
}

// Round 6
// 1369.349 us; speedup vs baseline: 1.8291x; 1.1021x over previous
//
#include <hip/hip_runtime.h>
#include <math.h>

#define CH 128

// ---------- bf16 helpers (bf16 = top 16 bits of f32, RTN encode) ----------
__device__ __forceinline__ unsigned int bf16enc1(float f) {
  unsigned int b = __float_as_uint(f);
  return (b + 0x7fffu + ((b >> 16) & 1u)) >> 16;
}
__device__ __forceinline__ unsigned int bf16pack2(float lo, float hi) {
  return bf16enc1(lo) | (bf16enc1(hi) << 16);
}
__device__ __forceinline__ float bf16lo(unsigned int u) { return __uint_as_float(u << 16); }
__device__ __forceinline__ float bf16hi(unsigned int u) { return __uint_as_float(u & 0xffff0000u); }

// ============================ CSR build ============================

__global__ void count_kernel(const int* __restrict__ dst, int n, int* __restrict__ cnt) {
  int stride = gridDim.x * blockDim.x;
  for (int e = blockIdx.x * blockDim.x + threadIdx.x; e < n; e += stride)
    atomicAdd(&cnt[dst[e]], 1);
}

// single-block exclusive scan, shuffle-based
__global__ __launch_bounds__(1024) void exscan_kernel(const int* __restrict__ cnt, int n,
                                                      int* __restrict__ off) {
  __shared__ int wsum[16];
  int lane = threadIdx.x & 63;
  int wid = threadIdx.x >> 6;
  int running = 0;
  for (int base = 0; base < n; base += 1024) {
    int i = base + (int)threadIdx.x;
    int v = (i < n) ? cnt[i] : 0;
    int x = v;
#pragma unroll
    for (int d = 1; d < 64; d <<= 1) {
      int t = __shfl_up(x, d);
      if (lane >= d) x += t;
    }
    if (lane == 63) wsum[wid] = x;
    __syncthreads();
    if (wid == 0) {
      int y = (lane < 16) ? wsum[lane] : 0;
#pragma unroll
      for (int d = 1; d < 16; d <<= 1) {
        int t = __shfl_up(y, d);
        if (lane >= d) y += t;
      }
      if (lane < 16) wsum[lane] = y;
    }
    __syncthreads();
    int wbase = wid ? wsum[wid - 1] : 0;
    if (i < n) off[i] = running + wbase + x - v;  // exclusive
    running += wsum[15];
    __syncthreads();  // wsum reused next tile
  }
  if (threadIdx.x == 0) off[n] = running;
}

// fill variants: scatter the per-edge payload into its CSR slot
__global__ void fill_kg_kernel(const int* __restrict__ head, const int* __restrict__ tail,
                               const int* __restrict__ type, int n,
                               const int* __restrict__ off, int* __restrict__ cur,
                               int2* __restrict__ pay) {
  int stride = gridDim.x * blockDim.x;
  for (int e = blockIdx.x * blockDim.x + threadIdx.x; e < n; e += stride) {
    int d = head[e];
    int p = off[d] + atomicAdd(&cur[d], 1);
    pay[p] = make_int2(tail[e], type[e] - 1);
  }
}

__global__ void fill_ex_kernel(const int* __restrict__ head, const int* __restrict__ tail,
                               int n, const int* __restrict__ off, int* __restrict__ cur,
                               int* __restrict__ pay /*int2 view*/, int* __restrict__ slot) {
  int stride = gridDim.x * blockDim.x;
  for (int e = blockIdx.x * blockDim.x + threadIdx.x; e < n; e += stride) {
    int d = head[e];
    int p = off[d] + atomicAdd(&cur[d], 1);
    pay[2 * (size_t)p] = tail[e];  // .y (aug weight) written later by attn
    slot[e] = p;
  }
}

__global__ void fill_it_kernel(const int* __restrict__ rows, const int* __restrict__ cols,
                               const float* __restrict__ vals, int n,
                               const int* __restrict__ off, int* __restrict__ cur,
                               int2* __restrict__ pay) {
  int stride = gridDim.x * blockDim.x;
  for (int e = blockIdx.x * blockDim.x + threadIdx.x; e < n; e += stride) {
    int d = rows[e];
    int p = off[d] + atomicAdd(&cur[d], 1);
    pay[p] = make_int2(cols[e], __float_as_int(vals[e]));
  }
}

// ============================ output init ============================
__global__ void init_out_kernel(const float* __restrict__ user, const float* __restrict__ ent,
                                float* __restrict__ out, int nu4, int ne4) {
  int i = blockIdx.x * blockDim.x + threadIdx.x;
  int half = nu4 + ne4;
  if (i >= 2 * half) return;
  int k = (i >= half) ? i - half : i;
  float4 v = (k < nu4) ? ((const float4*)user)[k] : ((const float4*)ent)[k - nu4];
  ((float4*)out)[i] = v;
}

// ============================ Q/K projection (fp32 in, bf16 out) ============================
__global__ __launch_bounds__(256) void qk_kernel(const float* __restrict__ user,
                                                 const float* __restrict__ ent,
                                                 const float* __restrict__ Wmat,
                                                 unsigned short* __restrict__ Out,
                                                 int n_users, int n_nodes) {
  __shared__ float X[32 * CH];
  const int t = threadIdx.x;
  const int row0 = blockIdx.x * 32;
  for (int i = t; i < 32 * 32; i += 256) {
    int r = i >> 5, c4 = i & 31;
    int row = row0 + r;
    float4 v = make_float4(0.f, 0.f, 0.f, 0.f);
    if (row < n_nodes) {
      const float* src = (row < n_users) ? (user + (size_t)row * CH)
                                         : (ent + (size_t)(row - n_users) * CH);
      v = ((const float4*)src)[c4];
    }
    ((float4*)X)[i] = v;
  }
  __syncthreads();
  const int c = t & 127;
  const int rg = t >> 7;
  float acc[16];
#pragma unroll
  for (int r = 0; r < 16; ++r) acc[r] = 0.f;
  for (int k4 = 0; k4 < CH; k4 += 4) {
    float w0 = Wmat[(k4 + 0) * CH + c];
    float w1 = Wmat[(k4 + 1) * CH + c];
    float w2 = Wmat[(k4 + 2) * CH + c];
    float w3 = Wmat[(k4 + 3) * CH + c];
#pragma unroll
    for (int r = 0; r < 16; ++r) {
      float4 x = *(const float4*)&X[(rg * 16 + r) * CH + k4];
      acc[r] += x.x * w0 + x.y * w1 + x.z * w2 + x.w * w3;
    }
  }
  for (int r = 0; r < 16; ++r) {
    int row = row0 + rg * 16 + r;
    if (row < n_nodes) Out[(size_t)row * CH + c] = (unsigned short)bf16enc1(acc[r]);
  }
}

// ============================ per-edge attention scores ============================
// 16 lanes per edge (4 edges/wave); each lane loads uint4 (8 bf16 ch) of Q and K.
// lanes 0-7 of the group cover head0 (ch 0-63), lanes 8-15 head1 (ch 64-127).
__global__ __launch_bounds__(256) void escore_kernel(const uint4* __restrict__ Q,
                                                     const uint4* __restrict__ K,
                                                     const int* __restrict__ eh,
                                                     const int* __restrict__ et,
                                                     const int* __restrict__ slot,
                                                     float2* __restrict__ scores, int n_edges) {
  int g = (int)((blockIdx.x * 256 + threadIdx.x) >> 4);  // edge id
  int gl = threadIdx.x & 15;                             // lane in 16-group
  if (g >= n_edges) return;
  int h = eh[g], tl = et[g];
  uint4 qu = Q[(size_t)h * 16 + gl];
  uint4 ku = K[(size_t)tl * 16 + gl];
  float p = bf16lo(qu.x) * bf16lo(ku.x) + bf16hi(qu.x) * bf16hi(ku.x);
  p += bf16lo(qu.y) * bf16lo(ku.y) + bf16hi(qu.y) * bf16hi(ku.y);
  p += bf16lo(qu.z) * bf16lo(ku.z) + bf16hi(qu.z) * bf16hi(ku.z);
  p += bf16lo(qu.w) * bf16lo(ku.w) + bf16hi(qu.w) * bf16hi(ku.w);
#pragma unroll
  for (int d = 1; d < 8; d <<= 1) p += __shfl_xor(p, d);  // reduce 8-lane half-groups
  float p1 = __shfl_xor(p, 8);  // lane 0 gets head1 total
  if (gl == 0) scores[slot[g]] = make_float2(p * 0.125f, p1 * 0.125f);
}

// ============================ scatter-softmax (contiguous per node) ============================
__global__ __launch_bounds__(256) void attn_kernel(const int* __restrict__ off,
                                                   const float2* __restrict__ scores,
                                                   int* __restrict__ pay_ex /*int2 view*/,
                                                   int n_nodes) {
  int wid = (int)((blockIdx.x * 256 + threadIdx.x) >> 6);
  int lane = threadIdx.x & 63;
  if (wid >= n_nodes) return;
  int o0 = off[wid], o1 = off[wid + 1];
  int deg = o1 - o0;
  if (deg == 0) return;
  float m0 = -3.4e38f, m1 = -3.4e38f;
  for (int i = lane; i < deg; i += 64) {
    float2 s = scores[o0 + i];
    m0 = fmaxf(m0, s.x);
    m1 = fmaxf(m1, s.y);
  }
#pragma unroll
  for (int d = 32; d; d >>= 1) {
    m0 = fmaxf(m0, __shfl_xor(m0, d));
    m1 = fmaxf(m1, __shfl_xor(m1, d));
  }
  float z0 = 0.f, z1 = 0.f;
  for (int i = lane; i < deg; i += 64) {
    float2 s = scores[o0 + i];
    z0 += expf(s.x - m0);
    z1 += expf(s.y - m1);
  }
#pragma unroll
  for (int d = 32; d; d >>= 1) {
    z0 += __shfl_xor(z0, d);
    z1 += __shfl_xor(z1, d);
  }
  float iz0 = 1.f / z0, iz1 = 1.f / z1;
  for (int i = lane; i < deg; i += 64) {
    float2 s = scores[o0 + i];
    float a = 0.5f * (expf(s.x - m0) * iz0 + expf(s.y - m1) * iz1);
    pay_ex[2 * (size_t)(o0 + i) + 1] = __float_as_int(a);
  }
}

// ============================ aggregation kernels (32 lanes/row, 2 rows/wave) ============================

// entity KG agg: acc over edges of src[tail]*(rscale)*weight[rel]; mean; l2norm.
// rscale_out written ONLY in hop 1 (hop-2 write raced with concurrent readers — R3 bug).
template <int HOP2>
__global__ __launch_bounds__(256) void entity_agg_kernel(
    const float* __restrict__ src, const int2* __restrict__ pay,
    const float* __restrict__ weight, const int* __restrict__ off,
    const float* __restrict__ rscale_in, float* __restrict__ Eout,
    float* __restrict__ rscale_out, float* __restrict__ res, int n) {
  int w = (int)((blockIdx.x * 256 + threadIdx.x) >> 5);
  int lane = threadIdx.x & 31;
  if (w >= n) return;
  int o0 = off[w], o1 = off[w + 1];
  float a0 = 0.f, a1 = 0.f, a2 = 0.f, a3 = 0.f;
#define EBODY(I)                                                      \
  {                                                                   \
    int2 pr = pay[I];                                                 \
    float rs = HOP2 ? rscale_in[pr.x] : 1.f;                          \
    float4 sv = ((const float4*)(src + (size_t)pr.x * CH))[lane];     \
    float4 wv = ((const float4*)(weight + (size_t)pr.y * CH))[lane];  \
    a0 += sv.x * wv.x * rs;                                           \
    a1 += sv.y * wv.y * rs;                                           \
    a2 += sv.z * wv.z * rs;                                           \
    a3 += sv.w * wv.w * rs;                                           \
  }
  int i = o0;
  for (; i + 4 <= o1; i += 4) { EBODY(i) EBODY(i + 1) EBODY(i + 2) EBODY(i + 3) }
  for (; i < o1; ++i) EBODY(i)
#undef EBODY
  int deg = o1 - o0;
  float inv = 1.f / (float)(deg > 0 ? deg : 1);
  a0 *= inv; a1 *= inv; a2 *= inv; a3 *= inv;
  float ss = a0 * a0 + a1 * a1 + a2 * a2 + a3 * a3;
#pragma unroll
  for (int d = 16; d; d >>= 1) ss += __shfl_xor(ss, d);  // within 32-lane half
  float scale = 1.f / fmaxf(sqrtf(ss), 1e-12f);
  ((float4*)(Eout + (size_t)w * CH))[lane] = make_float4(a0, a1, a2, a3);
  if (!HOP2 && lane == 0) rscale_out[w] = scale;
  float4* rp = (float4*)(res + (size_t)w * CH);
  float4 r = rp[lane];
  r.x += a0 * scale; r.y += a1 * scale; r.z += a2 * scale; r.w += a3 * scale;
  rp[lane] = r;
}

// preference-graph agg; BF=1 → bf16 source (hop2), BF=0 → fp32 user/ent (hop1)
template <int BF>
__global__ __launch_bounds__(256) void node_agg_kernel(
    const void* __restrict__ srcU, const void* __restrict__ srcE,
    const int2* __restrict__ pay, const int* __restrict__ off,
    uint2* __restrict__ Nout /*bf16x4 per lane, may be unused*/,
    float* __restrict__ res, int n, int n_users, int write_norm) {
  int w = (int)((blockIdx.x * 256 + threadIdx.x) >> 5);
  int lane = threadIdx.x & 31;
  if (w >= n) return;
  int o0 = off[w], o1 = off[w + 1];
  float a0 = 0.f, a1 = 0.f, a2 = 0.f, a3 = 0.f;
#define NBODY(I)                                                          \
  {                                                                       \
    int2 pr = pay[I];                                                     \
    float aw = __int_as_float(pr.y);                                      \
    int tl = pr.x;                                                        \
    int r_ = (tl < n_users) ? tl : tl - n_users;                          \
    if (BF) {                                                             \
      const uint2* b = (const uint2*)((tl < n_users) ? srcU : srcE);      \
      uint2 u = b[(size_t)r_ * 32 + lane];                                \
      a0 += bf16lo(u.x) * aw;                                             \
      a1 += bf16hi(u.x) * aw;                                             \
      a2 += bf16lo(u.y) * aw;                                             \
      a3 += bf16hi(u.y) * aw;                                             \
    } else {                                                              \
      const float* b = (const float*)((tl < n_users) ? srcU : srcE);      \
      float4 sv = ((const float4*)(b + (size_t)r_ * CH))[lane];           \
      a0 += sv.x * aw; a1 += sv.y * aw; a2 += sv.z * aw; a3 += sv.w * aw; \
    }                                                                     \
  }
  int i = o0;
  for (; i + 4 <= o1; i += 4) { NBODY(i) NBODY(i + 1) NBODY(i + 2) NBODY(i + 3) }
  for (; i < o1; ++i) NBODY(i)
#undef NBODY
  int deg = o1 - o0;
  float inv = 1.f / (float)(deg > 0 ? deg : 1);
  a0 *= inv; a1 *= inv; a2 *= inv; a3 *= inv;
  float ss = a0 * a0 + a1 * a1 + a2 * a2 + a3 * a3;
#pragma unroll
  for (int d = 16; d; d >>= 1) ss += __shfl_xor(ss, d);
  float scale = 1.f / fmaxf(sqrtf(ss), 1e-12f);
  float n0 = a0 * scale, n1 = a1 * scale, n2 = a2 * scale, n3 = a3 * scale;
  if (write_norm)
    Nout[(size_t)w * 32 + lane] = make_uint2(bf16pack2(n0, n1), bf16pack2(n2, n3));
  float4* rp = (float4*)(res + (size_t)w * CH);
  float4 r = rp[lane];
  r.x += n0; r.y += n1; r.z += n2; r.w += n3;
  rp[lane] = r;
}

// user = segment_sum(val * Eun[col]); l2norm; accumulate residual
__global__ __launch_bounds__(256) void user_agg_kernel(const float* __restrict__ Eun,
                                                       const int2* __restrict__ pay,
                                                       const int* __restrict__ off,
                                                       float* __restrict__ res, int n) {
  int w = (int)((blockIdx.x * 256 + threadIdx.x) >> 5);
  int lane = threadIdx.x & 31;
  if (w >= n) return;
  int o0 = off[w], o1 = off[w + 1];
  float a0 = 0.f, a1 = 0.f, a2 = 0.f, a3 = 0.f;
#define UBODY(I)                                                    \
  {                                                                 \
    int2 pr = pay[I];                                               \
    float v = __int_as_float(pr.y);                                 \
    float4 sv = ((const float4*)(Eun + (size_t)pr.x * CH))[lane];   \
    a0 += sv.x * v; a1 += sv.y * v; a2 += sv.z * v; a3 += sv.w * v; \
  }
  int i = o0;
  for (; i + 4 <= o1; i += 4) { UBODY(i) UBODY(i + 1) UBODY(i + 2) UBODY(i + 3) }
  for (; i < o1; ++i) UBODY(i)
#undef UBODY
  float ss = a0 * a0 + a1 * a1 + a2 * a2 + a3 * a3;
#pragma unroll
  for (int d = 16; d; d >>= 1) ss += __shfl_xor(ss, d);
  float scale = 1.f / fmaxf(sqrtf(ss), 1e-12f);
  float4* rp = (float4*)(res + (size_t)w * CH);
  float4 r = rp[lane];
  r.x += a0 * scale; r.y += a1 * scale; r.z += a2 * scale; r.w += a3 * scale;
  rp[lane] = r;
}

// ============================ host ============================

extern "C" void kernel_launch(void* const* d_in, const int* in_sizes, int n_in,
                              void* d_out, int out_size, void* d_ws, size_t ws_size,
                              hipStream_t stream) {
  const float* user_emb = (const float*)d_in[0];
  const float* ent_emb  = (const float*)d_in[1];
  const int*   edge_index = (const int*)d_in[2];
  const int*   edge_type  = (const int*)d_in[3];
  const int*   ex_index   = (const int*)d_in[4];
  const int*   it_rows = (const int*)d_in[6];
  const int*   it_cols = (const int*)d_in[7];
  const float* it_vals = (const float*)d_in[8];
  const float* weight  = (const float*)d_in[9];
  const float* W_Q = (const float*)d_in[11];
  const float* W_K = (const float*)d_in[12];

  const int n_users = in_sizes[0] / CH;
  const int n_ents  = in_sizes[1] / CH;
  const int n_nodes = n_users + n_ents;
  const int n_kg    = in_sizes[3];
  const int n_ex    = in_sizes[5];
  const int nnz     = in_sizes[8];

  const int* kg_head = edge_index;
  const int* kg_tail = edge_index + n_kg;
  const int* ex_head = ex_index;
  const int* ex_tail = ex_index + n_ex;

  // ---- workspace bump allocator (256B aligned) ----
  char* p = (char*)d_ws;
  auto alloc = [&](size_t bytes) -> char* {
    char* r = p;
    p += (bytes + 255) & ~(size_t)255;
    return r;
  };
  int2* pay_kg = (int2*)alloc((size_t)n_kg * 8);
  int2* pay_ex = (int2*)alloc((size_t)n_ex * 8);
  // union: phase A = slot_ex + scores ; phase B = pay_it (fill deferred past attn)
  size_t slotb = ((size_t)n_ex * 4 + 255) & ~(size_t)255;
  size_t unionA = slotb + (size_t)n_ex * 8;
  size_t unionB = (size_t)nnz * 8;
  char* uA = alloc(unionA > unionB ? unionA : unionB);
  int*    slot_ex = (int*)uA;
  float2* scores  = (float2*)(uA + slotb);
  int2*   pay_it  = (int2*)uA;
  char* cnt_base = alloc((size_t)(n_ents + n_nodes + n_users) * 4);
  int* cnt_kg = (int*)cnt_base;
  int* cnt_ex = cnt_kg + n_ents;
  int* cnt_it = cnt_ex + n_nodes;
  size_t cnt_bytes = (size_t)(n_ents + n_nodes + n_users) * 4;
  int* off_kg = (int*)alloc((size_t)(n_ents + 1) * 4);
  int* off_ex = (int*)alloc((size_t)(n_nodes + 1) * 4);
  int* off_it = (int*)alloc((size_t)(n_users + 1) * 4);
  // arena: phase A = Qbf,Kbf (bf16) ; phase B = EunA,EunB (f32) + rscale + Nn (bf16)
  size_t arenaA = (size_t)2 * n_nodes * CH * 2;
  size_t arenaB = (size_t)2 * n_ents * CH * 4 + (size_t)n_ents * 4 + 256 +
                  (size_t)n_nodes * CH * 2;
  char* arena = alloc(arenaA > arenaB ? arenaA : arenaB);
  unsigned int* Qbf = (unsigned int*)arena;  // [n_nodes][64] uint
  unsigned int* Kbf = Qbf + (size_t)n_nodes * 64;
  float* EunA = (float*)arena;
  float* EunB = EunA + (size_t)n_ents * CH;
  float* rscaleE = EunB + (size_t)n_ents * CH;
  uint2* Nnbf = (uint2*)(((uintptr_t)(rscaleE + n_ents) + 255) & ~(uintptr_t)255);

  float* res_user = (float*)d_out;
  float* res_ent  = (float*)d_out + (size_t)n_users * CH;
  float* res_node = (float*)d_out + (size_t)n_nodes * CH;

  // ---- 1. CSR counts + scans ----
  hipMemsetAsync(cnt_base, 0, cnt_bytes, stream);
  count_kernel<<<2048, 256, 0, stream>>>(kg_head, n_kg, cnt_kg);
  count_kernel<<<2048, 256, 0, stream>>>(ex_head, n_ex, cnt_ex);
  count_kernel<<<2048, 256, 0, stream>>>(it_rows, nnz, cnt_it);
  exscan_kernel<<<1, 1024, 0, stream>>>(cnt_kg, n_ents, off_kg);
  exscan_kernel<<<1, 1024, 0, stream>>>(cnt_ex, n_nodes, off_ex);
  exscan_kernel<<<1, 1024, 0, stream>>>(cnt_it, n_users, off_it);
  hipMemsetAsync(cnt_base, 0, cnt_bytes, stream);
  fill_kg_kernel<<<2048, 256, 0, stream>>>(kg_head, kg_tail, edge_type, n_kg, off_kg,
                                           cnt_kg, pay_kg);
  fill_ex_kernel<<<2048, 256, 0, stream>>>(ex_head, ex_tail, n_ex, off_ex, cnt_ex,
                                           (int*)pay_ex, slot_ex);

  // ---- 2. residual init ----
  {
    int nu4 = n_users * (CH / 4), ne4 = n_ents * (CH / 4);
    int total = 2 * (nu4 + ne4);
    init_out_kernel<<<(total + 255) / 256, 256, 0, stream>>>(user_emb, ent_emb,
                                                             (float*)d_out, nu4, ne4);
  }

  // ---- 3. attention (phase A of arena: Q/K bf16) ----
  {
    int blocks = (n_nodes + 31) / 32;
    qk_kernel<<<blocks, 256, 0, stream>>>(user_emb, ent_emb, W_Q, (unsigned short*)Qbf,
                                          n_users, n_nodes);
    qk_kernel<<<blocks, 256, 0, stream>>>(user_emb, ent_emb, W_K, (unsigned short*)Kbf,
                                          n_users, n_nodes);
  }
  escore_kernel<<<(n_ex + 15) / 16, 256, 0, stream>>>((const uint4*)Qbf, (const uint4*)Kbf,
                                                      ex_head, ex_tail, slot_ex, scores,
                                                      n_ex);
  attn_kernel<<<(n_nodes + 3) / 4, 256, 0, stream>>>(off_ex, scores, (int*)pay_ex, n_nodes);

  // ---- 4. interact CSR fill (overlaps dead slot/scores region) ----
  fill_it_kernel<<<2048, 256, 0, stream>>>(it_rows, it_cols, it_vals, nnz, off_it, cnt_it,
                                           pay_it);

  // ---- 5. hop 1 ----
  entity_agg_kernel<0><<<(n_ents + 7) / 8, 256, 0, stream>>>(
      ent_emb, pay_kg, weight, off_kg, nullptr, EunA, rscaleE, res_ent, n_ents);
  node_agg_kernel<0><<<(n_nodes + 7) / 8, 256, 0, stream>>>(
      user_emb, ent_emb, pay_ex, off_ex, Nnbf, res_node, n_nodes, n_users, 1);
  user_agg_kernel<<<(n_users + 7) / 8, 256, 0, stream>>>(EunA, pay_it, off_it, res_user,
                                                         n_users);

  // ---- 6. hop 2 ----
  entity_agg_kernel<1><<<(n_ents + 7) / 8, 256, 0, stream>>>(
      EunA, pay_kg, weight, off_kg, rscaleE, EunB, nullptr, res_ent, n_ents);
  node_agg_kernel<1><<<(n_nodes + 7) / 8, 256, 0, stream>>>(
      Nnbf, Nnbf + (size_t)n_users * 32, pay_ex, off_ex, Nnbf, res_node, n_nodes,
      n_users, 0);
  user_agg_kernel<<<(n_users + 7) / 8, 256, 0, stream>>>(EunB, pay_it, off_it, res_user,
                                                         n_users);
}

// Round 7
// 1214.854 us; speedup vs baseline: 2.0617x; 1.1272x over previous
//
#include <hip/hip_runtime.h>
#include <math.h>

#define CH 128
#define SCAN_TILE 2048  // 256 threads x 8 elements; guarantees n_tiles <= 64 for n <= 131072

// ---------- bf16 helpers (bf16 = top 16 bits of f32, RTN encode) ----------
__device__ __forceinline__ unsigned int bf16enc1(float f) {
  unsigned int b = __float_as_uint(f);
  return (b + 0x7fffu + ((b >> 16) & 1u)) >> 16;
}
__device__ __forceinline__ unsigned int bf16pack2(float lo, float hi) {
  return bf16enc1(lo) | (bf16enc1(hi) << 16);
}
__device__ __forceinline__ float bf16lo(unsigned int u) { return __uint_as_float(u << 16); }
__device__ __forceinline__ float bf16hi(unsigned int u) { return __uint_as_float(u & 0xffff0000u); }

// ============================ CSR build ============================

__global__ void count_kernel(const int* __restrict__ dst, int n, int* __restrict__ cnt) {
  int stride = gridDim.x * blockDim.x;
  for (int e = blockIdx.x * blockDim.x + threadIdx.x; e < n; e += stride)
    atomicAdd(&cnt[dst[e]], 1);
}

// ---- hierarchical exclusive scan (replaces the 89us single-block scan) ----
// phase 1: block per 2048-tile -> tile sum
__global__ __launch_bounds__(256) void scan_sum_kernel(const int* __restrict__ cnt, int n,
                                                       int* __restrict__ bsum) {
  __shared__ int red[4];
  int base = blockIdx.x * SCAN_TILE;
  int t = threadIdx.x;
  int idx = base + t * 8;
  int s = 0;
  if (idx + 8 <= n) {
    int4 a = *(const int4*)(cnt + idx);
    int4 b = *(const int4*)(cnt + idx + 4);
    s = a.x + a.y + a.z + a.w + b.x + b.y + b.z + b.w;
  } else {
    for (int i = 0; i < 8 && idx + i < n; ++i) s += cnt[idx + i];
  }
#pragma unroll
  for (int d = 32; d; d >>= 1) s += __shfl_xor(s, d);
  if ((t & 63) == 0) red[t >> 6] = s;
  __syncthreads();
  if (t == 0) bsum[blockIdx.x] = red[0] + red[1] + red[2] + red[3];
}

// phase 2: one wave exclusive-scans the (<=64) tile sums in place; writes off[n]=total
__global__ __launch_bounds__(64) void scan_mid_kernel(int* __restrict__ bsum, int n_tiles,
                                                      int* __restrict__ off, int n) {
  int lane = threadIdx.x;
  int v = (lane < n_tiles) ? bsum[lane] : 0;
  int x = v;
#pragma unroll
  for (int d = 1; d < 64; d <<= 1) {
    int t = __shfl_up(x, d);
    if (lane >= d) x += t;
  }
  if (lane < n_tiles) bsum[lane] = x - v;  // exclusive
  if (lane == 63) off[n] = x;              // grand total
}

// phase 3: block per tile: local exclusive scan + tile offset -> off[0..n)
__global__ __launch_bounds__(256) void scan_apply_kernel(const int* __restrict__ cnt, int n,
                                                         const int* __restrict__ bsum,
                                                         int* __restrict__ off) {
  __shared__ int wsums[4];
  int base = blockIdx.x * SCAN_TILE;
  int t = threadIdx.x;
  int idx = base + t * 8;
  int v[8];
  int s = 0;
  if (idx + 8 <= n) {
    int4 a = *(const int4*)(cnt + idx);
    int4 b = *(const int4*)(cnt + idx + 4);
    v[0] = a.x; v[1] = a.y; v[2] = a.z; v[3] = a.w;
    v[4] = b.x; v[5] = b.y; v[6] = b.z; v[7] = b.w;
    s = v[0] + v[1] + v[2] + v[3] + v[4] + v[5] + v[6] + v[7];
  } else {
#pragma unroll
    for (int i = 0; i < 8; ++i) {
      int j = idx + i;
      v[i] = (j < n) ? cnt[j] : 0;
      s += v[i];
    }
  }
  int lane = t & 63, wid = t >> 6;
  int x = s;
#pragma unroll
  for (int d = 1; d < 64; d <<= 1) {
    int tt = __shfl_up(x, d);
    if (lane >= d) x += tt;
  }
  if (lane == 63) wsums[wid] = x;
  __syncthreads();
  int wbase = 0;
  if (wid > 0) wbase += wsums[0];
  if (wid > 1) wbase += wsums[1];
  if (wid > 2) wbase += wsums[2];
  int run = bsum[blockIdx.x] + wbase + (x - s);  // exclusive prefix for this thread
#pragma unroll
  for (int i = 0; i < 8; ++i) {
    int j = idx + i;
    if (j < n) off[j] = run;
    run += v[i];
  }
}

// fill variants: scatter the per-edge payload into its CSR slot
__global__ void fill_kg_kernel(const int* __restrict__ head, const int* __restrict__ tail,
                               const int* __restrict__ type, int n,
                               const int* __restrict__ off, int* __restrict__ cur,
                               int2* __restrict__ pay) {
  int stride = gridDim.x * blockDim.x;
  for (int e = blockIdx.x * blockDim.x + threadIdx.x; e < n; e += stride) {
    int d = head[e];
    int p = off[d] + atomicAdd(&cur[d], 1);
    pay[p] = make_int2(tail[e], type[e] - 1);
  }
}

__global__ void fill_ex_kernel(const int* __restrict__ head, const int* __restrict__ tail,
                               int n, const int* __restrict__ off, int* __restrict__ cur,
                               int* __restrict__ pay /*int2 view*/, int* __restrict__ slot) {
  int stride = gridDim.x * blockDim.x;
  for (int e = blockIdx.x * blockDim.x + threadIdx.x; e < n; e += stride) {
    int d = head[e];
    int p = off[d] + atomicAdd(&cur[d], 1);
    pay[2 * (size_t)p] = tail[e];  // .y (aug weight) written later by attn
    slot[e] = p;
  }
}

__global__ void fill_it_kernel(const int* __restrict__ rows, const int* __restrict__ cols,
                               const float* __restrict__ vals, int n,
                               const int* __restrict__ off, int* __restrict__ cur,
                               int2* __restrict__ pay) {
  int stride = gridDim.x * blockDim.x;
  for (int e = blockIdx.x * blockDim.x + threadIdx.x; e < n; e += stride) {
    int d = rows[e];
    int p = off[d] + atomicAdd(&cur[d], 1);
    pay[p] = make_int2(cols[e], __float_as_int(vals[e]));
  }
}

// ============================ output init ============================
__global__ void init_out_kernel(const float* __restrict__ user, const float* __restrict__ ent,
                                float* __restrict__ out, int nu4, int ne4) {
  int i = blockIdx.x * blockDim.x + threadIdx.x;
  int half = nu4 + ne4;
  if (i >= 2 * half) return;
  int k = (i >= half) ? i - half : i;
  float4 v = (k < nu4) ? ((const float4*)user)[k] : ((const float4*)ent)[k - nu4];
  ((float4*)out)[i] = v;
}

// ============================ Q/K projection (fp32 in, bf16 out) ============================
__global__ __launch_bounds__(256) void qk_kernel(const float* __restrict__ user,
                                                 const float* __restrict__ ent,
                                                 const float* __restrict__ Wmat,
                                                 unsigned short* __restrict__ Out,
                                                 int n_users, int n_nodes) {
  __shared__ float X[32 * CH];
  const int t = threadIdx.x;
  const int row0 = blockIdx.x * 32;
  for (int i = t; i < 32 * 32; i += 256) {
    int r = i >> 5, c4 = i & 31;
    int row = row0 + r;
    float4 v = make_float4(0.f, 0.f, 0.f, 0.f);
    if (row < n_nodes) {
      const float* src = (row < n_users) ? (user + (size_t)row * CH)
                                         : (ent + (size_t)(row - n_users) * CH);
      v = ((const float4*)src)[c4];
    }
    ((float4*)X)[i] = v;
  }
  __syncthreads();
  const int c = t & 127;
  const int rg = t >> 7;
  float acc[16];
#pragma unroll
  for (int r = 0; r < 16; ++r) acc[r] = 0.f;
  for (int k4 = 0; k4 < CH; k4 += 4) {
    float w0 = Wmat[(k4 + 0) * CH + c];
    float w1 = Wmat[(k4 + 1) * CH + c];
    float w2 = Wmat[(k4 + 2) * CH + c];
    float w3 = Wmat[(k4 + 3) * CH + c];
#pragma unroll
    for (int r = 0; r < 16; ++r) {
      float4 x = *(const float4*)&X[(rg * 16 + r) * CH + k4];
      acc[r] += x.x * w0 + x.y * w1 + x.z * w2 + x.w * w3;
    }
  }
  for (int r = 0; r < 16; ++r) {
    int row = row0 + rg * 16 + r;
    if (row < n_nodes) Out[(size_t)row * CH + c] = (unsigned short)bf16enc1(acc[r]);
  }
}

// ============================ per-edge attention scores ============================
// 16 lanes per edge (4 edges/wave); each lane loads uint4 (8 bf16 ch) of Q and K.
__global__ __launch_bounds__(256) void escore_kernel(const uint4* __restrict__ Q,
                                                     const uint4* __restrict__ K,
                                                     const int* __restrict__ eh,
                                                     const int* __restrict__ et,
                                                     const int* __restrict__ slot,
                                                     float2* __restrict__ scores, int n_edges) {
  int g = (int)((blockIdx.x * 256 + threadIdx.x) >> 4);  // edge id
  int gl = threadIdx.x & 15;                             // lane in 16-group
  if (g >= n_edges) return;
  int h = eh[g], tl = et[g];
  uint4 qu = Q[(size_t)h * 16 + gl];
  uint4 ku = K[(size_t)tl * 16 + gl];
  float p = bf16lo(qu.x) * bf16lo(ku.x) + bf16hi(qu.x) * bf16hi(ku.x);
  p += bf16lo(qu.y) * bf16lo(ku.y) + bf16hi(qu.y) * bf16hi(ku.y);
  p += bf16lo(qu.z) * bf16lo(ku.z) + bf16hi(qu.z) * bf16hi(ku.z);
  p += bf16lo(qu.w) * bf16lo(ku.w) + bf16hi(qu.w) * bf16hi(ku.w);
#pragma unroll
  for (int d = 1; d < 8; d <<= 1) p += __shfl_xor(p, d);  // reduce 8-lane half-groups
  float p1 = __shfl_xor(p, 8);  // lane 0 gets head1 total
  if (gl == 0) scores[slot[g]] = make_float2(p * 0.125f, p1 * 0.125f);
}

// ============================ scatter-softmax (contiguous per node) ============================
__global__ __launch_bounds__(256) void attn_kernel(const int* __restrict__ off,
                                                   const float2* __restrict__ scores,
                                                   int* __restrict__ pay_ex /*int2 view*/,
                                                   int n_nodes) {
  int wid = (int)((blockIdx.x * 256 + threadIdx.x) >> 6);
  int lane = threadIdx.x & 63;
  if (wid >= n_nodes) return;
  int o0 = off[wid], o1 = off[wid + 1];
  int deg = o1 - o0;
  if (deg == 0) return;
  float m0 = -3.4e38f, m1 = -3.4e38f;
  for (int i = lane; i < deg; i += 64) {
    float2 s = scores[o0 + i];
    m0 = fmaxf(m0, s.x);
    m1 = fmaxf(m1, s.y);
  }
#pragma unroll
  for (int d = 32; d; d >>= 1) {
    m0 = fmaxf(m0, __shfl_xor(m0, d));
    m1 = fmaxf(m1, __shfl_xor(m1, d));
  }
  float z0 = 0.f, z1 = 0.f;
  for (int i = lane; i < deg; i += 64) {
    float2 s = scores[o0 + i];
    z0 += expf(s.x - m0);
    z1 += expf(s.y - m1);
  }
#pragma unroll
  for (int d = 32; d; d >>= 1) {
    z0 += __shfl_xor(z0, d);
    z1 += __shfl_xor(z1, d);
  }
  float iz0 = 1.f / z0, iz1 = 1.f / z1;
  for (int i = lane; i < deg; i += 64) {
    float2 s = scores[o0 + i];
    float a = 0.5f * (expf(s.x - m0) * iz0 + expf(s.y - m1) * iz1);
    pay_ex[2 * (size_t)(o0 + i) + 1] = __float_as_int(a);
  }
}

// ============================ aggregation kernels (32 lanes/row, 2 rows/wave) ============================

// entity KG agg; rscale_out written ONLY in hop 1 (hop-2 write raced — R3 bug).
template <int HOP2>
__global__ __launch_bounds__(256) void entity_agg_kernel(
    const float* __restrict__ src, const int2* __restrict__ pay,
    const float* __restrict__ weight, const int* __restrict__ off,
    const float* __restrict__ rscale_in, float* __restrict__ Eout,
    float* __restrict__ rscale_out, float* __restrict__ res, int n) {
  int w = (int)((blockIdx.x * 256 + threadIdx.x) >> 5);
  int lane = threadIdx.x & 31;
  if (w >= n) return;
  int o0 = off[w], o1 = off[w + 1];
  float a0 = 0.f, a1 = 0.f, a2 = 0.f, a3 = 0.f;
#define EBODY(I)                                                      \
  {                                                                   \
    int2 pr = pay[I];                                                 \
    float rs = HOP2 ? rscale_in[pr.x] : 1.f;                          \
    float4 sv = ((const float4*)(src + (size_t)pr.x * CH))[lane];     \
    float4 wv = ((const float4*)(weight + (size_t)pr.y * CH))[lane];  \
    a0 += sv.x * wv.x * rs;                                           \
    a1 += sv.y * wv.y * rs;                                           \
    a2 += sv.z * wv.z * rs;                                           \
    a3 += sv.w * wv.w * rs;                                           \
  }
  int i = o0;
  for (; i + 4 <= o1; i += 4) { EBODY(i) EBODY(i + 1) EBODY(i + 2) EBODY(i + 3) }
  for (; i < o1; ++i) EBODY(i)
#undef EBODY
  int deg = o1 - o0;
  float inv = 1.f / (float)(deg > 0 ? deg : 1);
  a0 *= inv; a1 *= inv; a2 *= inv; a3 *= inv;
  float ss = a0 * a0 + a1 * a1 + a2 * a2 + a3 * a3;
#pragma unroll
  for (int d = 16; d; d >>= 1) ss += __shfl_xor(ss, d);  // within 32-lane half
  float scale = 1.f / fmaxf(sqrtf(ss), 1e-12f);
  ((float4*)(Eout + (size_t)w * CH))[lane] = make_float4(a0, a1, a2, a3);
  if (!HOP2 && lane == 0) rscale_out[w] = scale;
  float4* rp = (float4*)(res + (size_t)w * CH);
  float4 r = rp[lane];
  r.x += a0 * scale; r.y += a1 * scale; r.z += a2 * scale; r.w += a3 * scale;
  rp[lane] = r;
}

// preference-graph agg; BF=1 → bf16 source (hop2), BF=0 → fp32 user/ent (hop1)
template <int BF>
__global__ __launch_bounds__(256) void node_agg_kernel(
    const void* __restrict__ srcU, const void* __restrict__ srcE,
    const int2* __restrict__ pay, const int* __restrict__ off,
    uint2* __restrict__ Nout /*bf16x4 per lane, may be unused*/,
    float* __restrict__ res, int n, int n_users, int write_norm) {
  int w = (int)((blockIdx.x * 256 + threadIdx.x) >> 5);
  int lane = threadIdx.x & 31;
  if (w >= n) return;
  int o0 = off[w], o1 = off[w + 1];
  float a0 = 0.f, a1 = 0.f, a2 = 0.f, a3 = 0.f;
#define NBODY(I)                                                          \
  {                                                                       \
    int2 pr = pay[I];                                                     \
    float aw = __int_as_float(pr.y);                                      \
    int tl = pr.x;                                                        \
    int r_ = (tl < n_users) ? tl : tl - n_users;                          \
    if (BF) {                                                             \
      const uint2* b = (const uint2*)((tl < n_users) ? srcU : srcE);      \
      uint2 u = b[(size_t)r_ * 32 + lane];                                \
      a0 += bf16lo(u.x) * aw;                                             \
      a1 += bf16hi(u.x) * aw;                                             \
      a2 += bf16lo(u.y) * aw;                                             \
      a3 += bf16hi(u.y) * aw;                                             \
    } else {                                                              \
      const float* b = (const float*)((tl < n_users) ? srcU : srcE);      \
      float4 sv = ((const float4*)(b + (size_t)r_ * CH))[lane];           \
      a0 += sv.x * aw; a1 += sv.y * aw; a2 += sv.z * aw; a3 += sv.w * aw; \
    }                                                                     \
  }
  int i = o0;
  for (; i + 4 <= o1; i += 4) { NBODY(i) NBODY(i + 1) NBODY(i + 2) NBODY(i + 3) }
  for (; i < o1; ++i) NBODY(i)
#undef NBODY
  int deg = o1 - o0;
  float inv = 1.f / (float)(deg > 0 ? deg : 1);
  a0 *= inv; a1 *= inv; a2 *= inv; a3 *= inv;
  float ss = a0 * a0 + a1 * a1 + a2 * a2 + a3 * a3;
#pragma unroll
  for (int d = 16; d; d >>= 1) ss += __shfl_xor(ss, d);
  float scale = 1.f / fmaxf(sqrtf(ss), 1e-12f);
  float n0 = a0 * scale, n1 = a1 * scale, n2 = a2 * scale, n3 = a3 * scale;
  if (write_norm)
    Nout[(size_t)w * 32 + lane] = make_uint2(bf16pack2(n0, n1), bf16pack2(n2, n3));
  float4* rp = (float4*)(res + (size_t)w * CH);
  float4 r = rp[lane];
  r.x += n0; r.y += n1; r.z += n2; r.w += n3;
  rp[lane] = r;
}

// user = segment_sum(val * Eun[col]); l2norm; accumulate residual
__global__ __launch_bounds__(256) void user_agg_kernel(const float* __restrict__ Eun,
                                                       const int2* __restrict__ pay,
                                                       const int* __restrict__ off,
                                                       float* __restrict__ res, int n) {
  int w = (int)((blockIdx.x * 256 + threadIdx.x) >> 5);
  int lane = threadIdx.x & 31;
  if (w >= n) return;
  int o0 = off[w], o1 = off[w + 1];
  float a0 = 0.f, a1 = 0.f, a2 = 0.f, a3 = 0.f;
#define UBODY(I)                                                    \
  {                                                                 \
    int2 pr = pay[I];                                               \
    float v = __int_as_float(pr.y);                                 \
    float4 sv = ((const float4*)(Eun + (size_t)pr.x * CH))[lane];   \
    a0 += sv.x * v; a1 += sv.y * v; a2 += sv.z * v; a3 += sv.w * v; \
  }
  int i = o0;
  for (; i + 4 <= o1; i += 4) { UBODY(i) UBODY(i + 1) UBODY(i + 2) UBODY(i + 3) }
  for (; i < o1; ++i) UBODY(i)
#undef UBODY
  float ss = a0 * a0 + a1 * a1 + a2 * a2 + a3 * a3;
#pragma unroll
  for (int d = 16; d; d >>= 1) ss += __shfl_xor(ss, d);
  float scale = 1.f / fmaxf(sqrtf(ss), 1e-12f);
  float4* rp = (float4*)(res + (size_t)w * CH);
  float4 r = rp[lane];
  r.x += a0 * scale; r.y += a1 * scale; r.z += a2 * scale; r.w += a3 * scale;
  rp[lane] = r;
}

// ============================ host ============================

extern "C" void kernel_launch(void* const* d_in, const int* in_sizes, int n_in,
                              void* d_out, int out_size, void* d_ws, size_t ws_size,
                              hipStream_t stream) {
  const float* user_emb = (const float*)d_in[0];
  const float* ent_emb  = (const float*)d_in[1];
  const int*   edge_index = (const int*)d_in[2];
  const int*   edge_type  = (const int*)d_in[3];
  const int*   ex_index   = (const int*)d_in[4];
  const int*   it_rows = (const int*)d_in[6];
  const int*   it_cols = (const int*)d_in[7];
  const float* it_vals = (const float*)d_in[8];
  const float* weight  = (const float*)d_in[9];
  const float* W_Q = (const float*)d_in[11];
  const float* W_K = (const float*)d_in[12];

  const int n_users = in_sizes[0] / CH;
  const int n_ents  = in_sizes[1] / CH;
  const int n_nodes = n_users + n_ents;
  const int n_kg    = in_sizes[3];
  const int n_ex    = in_sizes[5];
  const int nnz     = in_sizes[8];

  const int* kg_head = edge_index;
  const int* kg_tail = edge_index + n_kg;
  const int* ex_head = ex_index;
  const int* ex_tail = ex_index + n_ex;

  // ---- workspace bump allocator (256B aligned) ----
  char* p = (char*)d_ws;
  auto alloc = [&](size_t bytes) -> char* {
    char* r = p;
    p += (bytes + 255) & ~(size_t)255;
    return r;
  };
  int2* pay_kg = (int2*)alloc((size_t)n_kg * 8);
  int2* pay_ex = (int2*)alloc((size_t)n_ex * 8);
  // union: phase A = slot_ex + scores ; phase B = pay_it (fill deferred past attn)
  size_t slotb = ((size_t)n_ex * 4 + 255) & ~(size_t)255;
  size_t unionA = slotb + (size_t)n_ex * 8;
  size_t unionB = (size_t)nnz * 8;
  char* uA = alloc(unionA > unionB ? unionA : unionB);
  int*    slot_ex = (int*)uA;
  float2* scores  = (float2*)(uA + slotb);
  int2*   pay_it  = (int2*)uA;
  char* cnt_base = alloc((size_t)(n_ents + n_nodes + n_users) * 4);
  int* cnt_kg = (int*)cnt_base;
  int* cnt_ex = cnt_kg + n_ents;
  int* cnt_it = cnt_ex + n_nodes;
  size_t cnt_bytes = (size_t)(n_ents + n_nodes + n_users) * 4;
  int* off_kg = (int*)alloc((size_t)(n_ents + 1) * 4);
  int* off_ex = (int*)alloc((size_t)(n_nodes + 1) * 4);
  int* off_it = (int*)alloc((size_t)(n_users + 1) * 4);
  int* bsum_kg = (int*)alloc(64 * 4);
  int* bsum_ex = (int*)alloc(64 * 4);
  int* bsum_it = (int*)alloc(64 * 4);
  // arena: phase A = Qbf,Kbf (bf16) ; phase B = EunA,EunB (f32) + rscale + Nn (bf16)
  size_t arenaA = (size_t)2 * n_nodes * CH * 2;
  size_t arenaB = (size_t)2 * n_ents * CH * 4 + (size_t)n_ents * 4 + 256 +
                  (size_t)n_nodes * CH * 2;
  char* arena = alloc(arenaA > arenaB ? arenaA : arenaB);
  unsigned int* Qbf = (unsigned int*)arena;  // [n_nodes][64] uint
  unsigned int* Kbf = Qbf + (size_t)n_nodes * 64;
  float* EunA = (float*)arena;
  float* EunB = EunA + (size_t)n_ents * CH;
  float* rscaleE = EunB + (size_t)n_ents * CH;
  uint2* Nnbf = (uint2*)(((uintptr_t)(rscaleE + n_ents) + 255) & ~(uintptr_t)255);

  float* res_user = (float*)d_out;
  float* res_ent  = (float*)d_out + (size_t)n_users * CH;
  float* res_node = (float*)d_out + (size_t)n_nodes * CH;

  const int t_kg = (n_ents + SCAN_TILE - 1) / SCAN_TILE;
  const int t_ex = (n_nodes + SCAN_TILE - 1) / SCAN_TILE;
  const int t_it = (n_users + SCAN_TILE - 1) / SCAN_TILE;

  // ---- 1. CSR counts + hierarchical scans ----
  hipMemsetAsync(cnt_base, 0, cnt_bytes, stream);
  count_kernel<<<2048, 256, 0, stream>>>(kg_head, n_kg, cnt_kg);
  count_kernel<<<2048, 256, 0, stream>>>(ex_head, n_ex, cnt_ex);
  count_kernel<<<2048, 256, 0, stream>>>(it_rows, nnz, cnt_it);
  scan_sum_kernel<<<t_kg, 256, 0, stream>>>(cnt_kg, n_ents, bsum_kg);
  scan_sum_kernel<<<t_ex, 256, 0, stream>>>(cnt_ex, n_nodes, bsum_ex);
  scan_sum_kernel<<<t_it, 256, 0, stream>>>(cnt_it, n_users, bsum_it);
  scan_mid_kernel<<<1, 64, 0, stream>>>(bsum_kg, t_kg, off_kg, n_ents);
  scan_mid_kernel<<<1, 64, 0, stream>>>(bsum_ex, t_ex, off_ex, n_nodes);
  scan_mid_kernel<<<1, 64, 0, stream>>>(bsum_it, t_it, off_it, n_users);
  scan_apply_kernel<<<t_kg, 256, 0, stream>>>(cnt_kg, n_ents, bsum_kg, off_kg);
  scan_apply_kernel<<<t_ex, 256, 0, stream>>>(cnt_ex, n_nodes, bsum_ex, off_ex);
  scan_apply_kernel<<<t_it, 256, 0, stream>>>(cnt_it, n_users, bsum_it, off_it);
  hipMemsetAsync(cnt_base, 0, cnt_bytes, stream);
  fill_kg_kernel<<<2048, 256, 0, stream>>>(kg_head, kg_tail, edge_type, n_kg, off_kg,
                                           cnt_kg, pay_kg);
  fill_ex_kernel<<<2048, 256, 0, stream>>>(ex_head, ex_tail, n_ex, off_ex, cnt_ex,
                                           (int*)pay_ex, slot_ex);

  // ---- 2. residual init ----
  {
    int nu4 = n_users * (CH / 4), ne4 = n_ents * (CH / 4);
    int total = 2 * (nu4 + ne4);
    init_out_kernel<<<(total + 255) / 256, 256, 0, stream>>>(user_emb, ent_emb,
                                                             (float*)d_out, nu4, ne4);
  }

  // ---- 3. attention (phase A of arena: Q/K bf16) ----
  {
    int blocks = (n_nodes + 31) / 32;
    qk_kernel<<<blocks, 256, 0, stream>>>(user_emb, ent_emb, W_Q, (unsigned short*)Qbf,
                                          n_users, n_nodes);
    qk_kernel<<<blocks, 256, 0, stream>>>(user_emb, ent_emb, W_K, (unsigned short*)Kbf,
                                          n_users, n_nodes);
  }
  escore_kernel<<<(n_ex + 15) / 16, 256, 0, stream>>>((const uint4*)Qbf, (const uint4*)Kbf,
                                                      ex_head, ex_tail, slot_ex, scores,
                                                      n_ex);
  attn_kernel<<<(n_nodes + 3) / 4, 256, 0, stream>>>(off_ex, scores, (int*)pay_ex, n_nodes);

  // ---- 4. interact CSR fill (overlaps dead slot/scores region) ----
  fill_it_kernel<<<2048, 256, 0, stream>>>(it_rows, it_cols, it_vals, nnz, off_it, cnt_it,
                                           pay_it);

  // ---- 5. hop 1 ----
  entity_agg_kernel<0><<<(n_ents + 7) / 8, 256, 0, stream>>>(
      ent_emb, pay_kg, weight, off_kg, nullptr, EunA, rscaleE, res_ent, n_ents);
  node_agg_kernel<0><<<(n_nodes + 7) / 8, 256, 0, stream>>>(
      user_emb, ent_emb, pay_ex, off_ex, Nnbf, res_node, n_nodes, n_users, 1);
  user_agg_kernel<<<(n_users + 7) / 8, 256, 0, stream>>>(EunA, pay_it, off_it, res_user,
                                                         n_users);

  // ---- 6. hop 2 ----
  entity_agg_kernel<1><<<(n_ents + 7) / 8, 256, 0, stream>>>(
      EunA, pay_kg, weight, off_kg, rscaleE, EunB, nullptr, res_ent, n_ents);
  node_agg_kernel<1><<<(n_nodes + 7) / 8, 256, 0, stream>>>(
      Nnbf, Nnbf + (size_t)n_users * 32, pay_ex, off_ex, Nnbf, res_node, n_nodes,
      n_users, 0);
  user_agg_kernel<<<(n_users + 7) / 8, 256, 0, stream>>>(EunB, pay_it, off_it, res_user,
                                                         n_users);
}

// Round 8
// 1072.365 us; speedup vs baseline: 2.3356x; 1.1329x over previous
//
#include <hip/hip_runtime.h>
#include <math.h>

#define CH 128
#define SCAN_TILE 2048

typedef __attribute__((ext_vector_type(8))) short short8v;
typedef __attribute__((ext_vector_type(4))) float float4v;

// ---------- bf16 helpers (bf16 = top 16 bits of f32, RTN encode) ----------
__device__ __forceinline__ unsigned int bf16enc1(float f) {
  unsigned int b = __float_as_uint(f);
  return (b + 0x7fffu + ((b >> 16) & 1u)) >> 16;
}
__device__ __forceinline__ unsigned int bf16pack2(float lo, float hi) {
  return bf16enc1(lo) | (bf16enc1(hi) << 16);
}
__device__ __forceinline__ float bf16lo(unsigned int u) { return __uint_as_float(u << 16); }
__device__ __forceinline__ float bf16hi(unsigned int u) { return __uint_as_float(u & 0xffff0000u); }

// ============================ CSR build ============================

__global__ void count_kernel(const int* __restrict__ dst, int n, int* __restrict__ cnt) {
  int stride = gridDim.x * blockDim.x;
  for (int e = blockIdx.x * blockDim.x + threadIdx.x; e < n; e += stride)
    atomicAdd(&cnt[dst[e]], 1);
}

// ---- hierarchical exclusive scan ----
__global__ __launch_bounds__(256) void scan_sum_kernel(const int* __restrict__ cnt, int n,
                                                       int* __restrict__ bsum) {
  __shared__ int red[4];
  int base = blockIdx.x * SCAN_TILE;
  int t = threadIdx.x;
  int idx = base + t * 8;
  int s = 0;
  if (idx + 8 <= n) {
    int4 a = *(const int4*)(cnt + idx);
    int4 b = *(const int4*)(cnt + idx + 4);
    s = a.x + a.y + a.z + a.w + b.x + b.y + b.z + b.w;
  } else {
    for (int i = 0; i < 8 && idx + i < n; ++i) s += cnt[idx + i];
  }
#pragma unroll
  for (int d = 32; d; d >>= 1) s += __shfl_xor(s, d);
  if ((t & 63) == 0) red[t >> 6] = s;
  __syncthreads();
  if (t == 0) bsum[blockIdx.x] = red[0] + red[1] + red[2] + red[3];
}

__global__ __launch_bounds__(64) void scan_mid_kernel(int* __restrict__ bsum, int n_tiles,
                                                      int* __restrict__ off, int n) {
  int lane = threadIdx.x;
  int v = (lane < n_tiles) ? bsum[lane] : 0;
  int x = v;
#pragma unroll
  for (int d = 1; d < 64; d <<= 1) {
    int t = __shfl_up(x, d);
    if (lane >= d) x += t;
  }
  if (lane < n_tiles) bsum[lane] = x - v;
  if (lane == 63) off[n] = x;
}

__global__ __launch_bounds__(256) void scan_apply_kernel(const int* __restrict__ cnt, int n,
                                                         const int* __restrict__ bsum,
                                                         int* __restrict__ off) {
  __shared__ int wsums[4];
  int base = blockIdx.x * SCAN_TILE;
  int t = threadIdx.x;
  int idx = base + t * 8;
  int v[8];
  int s = 0;
  if (idx + 8 <= n) {
    int4 a = *(const int4*)(cnt + idx);
    int4 b = *(const int4*)(cnt + idx + 4);
    v[0] = a.x; v[1] = a.y; v[2] = a.z; v[3] = a.w;
    v[4] = b.x; v[5] = b.y; v[6] = b.z; v[7] = b.w;
    s = v[0] + v[1] + v[2] + v[3] + v[4] + v[5] + v[6] + v[7];
  } else {
#pragma unroll
    for (int i = 0; i < 8; ++i) {
      int j = idx + i;
      v[i] = (j < n) ? cnt[j] : 0;
      s += v[i];
    }
  }
  int lane = t & 63, wid = t >> 6;
  int x = s;
#pragma unroll
  for (int d = 1; d < 64; d <<= 1) {
    int tt = __shfl_up(x, d);
    if (lane >= d) x += tt;
  }
  if (lane == 63) wsums[wid] = x;
  __syncthreads();
  int wbase = 0;
  if (wid > 0) wbase += wsums[0];
  if (wid > 1) wbase += wsums[1];
  if (wid > 2) wbase += wsums[2];
  int run = bsum[blockIdx.x] + wbase + (x - s);
#pragma unroll
  for (int i = 0; i < 8; ++i) {
    int j = idx + i;
    if (j < n) off[j] = run;
    run += v[i];
  }
}

// fill variants
__global__ void fill_kg_kernel(const int* __restrict__ head, const int* __restrict__ tail,
                               const int* __restrict__ type, int n,
                               const int* __restrict__ off, int* __restrict__ cur,
                               int2* __restrict__ pay) {
  int stride = gridDim.x * blockDim.x;
  for (int e = blockIdx.x * blockDim.x + threadIdx.x; e < n; e += stride) {
    int d = head[e];
    int p = off[d] + atomicAdd(&cur[d], 1);
    pay[p] = make_int2(tail[e], type[e] - 1);
  }
}

__global__ void fill_ex_kernel(const int* __restrict__ head, const int* __restrict__ tail,
                               int n, const int* __restrict__ off, int* __restrict__ cur,
                               int* __restrict__ pay /*int2 view*/, int* __restrict__ slot) {
  int stride = gridDim.x * blockDim.x;
  for (int e = blockIdx.x * blockDim.x + threadIdx.x; e < n; e += stride) {
    int d = head[e];
    int p = off[d] + atomicAdd(&cur[d], 1);
    pay[2 * (size_t)p] = tail[e];
    slot[e] = p;
  }
}

__global__ void fill_it_kernel(const int* __restrict__ rows, const int* __restrict__ cols,
                               const float* __restrict__ vals, int n,
                               const int* __restrict__ off, int* __restrict__ cur,
                               int2* __restrict__ pay) {
  int stride = gridDim.x * blockDim.x;
  for (int e = blockIdx.x * blockDim.x + threadIdx.x; e < n; e += stride) {
    int d = rows[e];
    int p = off[d] + atomicAdd(&cur[d], 1);
    pay[p] = make_int2(cols[e], __float_as_int(vals[e]));
  }
}

// ============================ output init ============================
__global__ void init_out_kernel(const float* __restrict__ user, const float* __restrict__ ent,
                                float* __restrict__ out, int nu4, int ne4) {
  int i = blockIdx.x * blockDim.x + threadIdx.x;
  int half = nu4 + ne4;
  if (i >= 2 * half) return;
  int k = (i >= half) ? i - half : i;
  float4 v = (k < nu4) ? ((const float4*)user)[k] : ((const float4*)ent)[k - nu4];
  ((float4*)out)[i] = v;
}

// ============================ W transpose+bf16 (once) ============================
// WtX[c][k] = bf16(WX[k][c]) — makes MFMA B-fragments contiguous 16B loads
__global__ __launch_bounds__(256) void wtrans_kernel(const float* __restrict__ WQ,
                                                     const float* __restrict__ WK,
                                                     unsigned short* __restrict__ WtQ,
                                                     unsigned short* __restrict__ WtK) {
  int idx = blockIdx.x * 256 + threadIdx.x;
  if (idx >= CH * CH) return;
  int k = idx >> 7, c = idx & 127;
  WtQ[c * CH + k] = (unsigned short)bf16enc1(WQ[idx]);
  WtK[c * CH + k] = (unsigned short)bf16enc1(WK[idx]);
}

// ============================ fused MFMA Q/K projection ============================
// 64 rows/block, 4 waves; each wave: 16 rows x 128 cols x {Q,K} via 64 mfma 16x16x32.
// A-frag: row=l&15, k=(l>>4)*8+j ; B-frag: col=l&15, same k ; D: col=l&15, row=(l>>4)*4+reg.
// Also mirrors the bf16-staged X tile to global Xnbf (if non-null) for the hop-1 gathers.
__global__ __launch_bounds__(256) void qk_mfma_kernel(
    const float* __restrict__ user, const float* __restrict__ ent,
    const unsigned short* __restrict__ WtQ, const unsigned short* __restrict__ WtK,
    unsigned short* __restrict__ OutQ, unsigned short* __restrict__ OutK,
    unsigned int* __restrict__ Xnbf, int n_users, int n_nodes) {
  __shared__ unsigned short Xb[64 * 136];  // pad 128->136: row-stride bank fix
  const int t = threadIdx.x;
  const int row0 = blockIdx.x * 64;
  for (int u = t; u < 64 * 64; u += 256) {  // float2 units
    int r = u >> 6, c2 = u & 63;
    int row = row0 + r;
    float2 v = make_float2(0.f, 0.f);
    if (row < n_nodes) {
      const float* src = (row < n_users) ? (user + (size_t)row * CH)
                                         : (ent + (size_t)(row - n_users) * CH);
      v = ((const float2*)src)[c2];
    }
    unsigned int pk = bf16pack2(v.x, v.y);
    *(unsigned int*)&Xb[r * 136 + c2 * 2] = pk;
    if (Xnbf != nullptr && row < n_nodes) Xnbf[(size_t)row * 64 + c2] = pk;
  }
  __syncthreads();
  const int w = t >> 6;
  const int l = t & 63;
  const int rl = (w << 4) + (l & 15);  // local row for A-frag
  const int lg = l >> 4;               // k-group
  short8v a[4];
#pragma unroll
  for (int kk = 0; kk < 4; ++kk)
    a[kk] = *(const short8v*)&Xb[rl * 136 + kk * 32 + lg * 8];
#pragma unroll
  for (int tb = 0; tb < 2; ++tb) {
    const unsigned short* W = tb ? WtK : WtQ;
    unsigned short* O = tb ? OutK : OutQ;
#pragma unroll
    for (int ct = 0; ct < 8; ++ct) {
      float4v acc = {0.f, 0.f, 0.f, 0.f};
#pragma unroll
      for (int kk = 0; kk < 4; ++kk) {
        short8v b = *(const short8v*)&W[(ct * 16 + (l & 15)) * CH + kk * 32 + lg * 8];
        acc = __builtin_amdgcn_mfma_f32_16x16x32_bf16(a[kk], b, acc, 0, 0, 0);
      }
      int col = ct * 16 + (l & 15);
#pragma unroll
      for (int i = 0; i < 4; ++i) {
        int row = row0 + (w << 4) + lg * 4 + i;
        if (row < n_nodes) O[(size_t)row * CH + col] = (unsigned short)bf16enc1(acc[i]);
      }
    }
  }
}

// ============================ per-edge attention scores ============================
__global__ __launch_bounds__(256) void escore_kernel(const uint4* __restrict__ Q,
                                                     const uint4* __restrict__ K,
                                                     const int* __restrict__ eh,
                                                     const int* __restrict__ et,
                                                     const int* __restrict__ slot,
                                                     float2* __restrict__ scores, int n_edges) {
  int g = (int)((blockIdx.x * 256 + threadIdx.x) >> 4);
  int gl = threadIdx.x & 15;
  if (g >= n_edges) return;
  int h = eh[g], tl = et[g];
  uint4 qu = Q[(size_t)h * 16 + gl];
  uint4 ku = K[(size_t)tl * 16 + gl];
  float p = bf16lo(qu.x) * bf16lo(ku.x) + bf16hi(qu.x) * bf16hi(ku.x);
  p += bf16lo(qu.y) * bf16lo(ku.y) + bf16hi(qu.y) * bf16hi(ku.y);
  p += bf16lo(qu.z) * bf16lo(ku.z) + bf16hi(qu.z) * bf16hi(ku.z);
  p += bf16lo(qu.w) * bf16lo(ku.w) + bf16hi(qu.w) * bf16hi(ku.w);
#pragma unroll
  for (int d = 1; d < 8; d <<= 1) p += __shfl_xor(p, d);
  float p1 = __shfl_xor(p, 8);
  if (gl == 0) scores[slot[g]] = make_float2(p * 0.125f, p1 * 0.125f);
}

// ============================ scatter-softmax ============================
__global__ __launch_bounds__(256) void attn_kernel(const int* __restrict__ off,
                                                   const float2* __restrict__ scores,
                                                   int* __restrict__ pay_ex,
                                                   int n_nodes) {
  int wid = (int)((blockIdx.x * 256 + threadIdx.x) >> 6);
  int lane = threadIdx.x & 63;
  if (wid >= n_nodes) return;
  int o0 = off[wid], o1 = off[wid + 1];
  int deg = o1 - o0;
  if (deg == 0) return;
  float m0 = -3.4e38f, m1 = -3.4e38f;
  for (int i = lane; i < deg; i += 64) {
    float2 s = scores[o0 + i];
    m0 = fmaxf(m0, s.x);
    m1 = fmaxf(m1, s.y);
  }
#pragma unroll
  for (int d = 32; d; d >>= 1) {
    m0 = fmaxf(m0, __shfl_xor(m0, d));
    m1 = fmaxf(m1, __shfl_xor(m1, d));
  }
  float z0 = 0.f, z1 = 0.f;
  for (int i = lane; i < deg; i += 64) {
    float2 s = scores[o0 + i];
    z0 += expf(s.x - m0);
    z1 += expf(s.y - m1);
  }
#pragma unroll
  for (int d = 32; d; d >>= 1) {
    z0 += __shfl_xor(z0, d);
    z1 += __shfl_xor(z1, d);
  }
  float iz0 = 1.f / z0, iz1 = 1.f / z1;
  for (int i = lane; i < deg; i += 64) {
    float2 s = scores[o0 + i];
    float a = 0.5f * (expf(s.x - m0) * iz0 + expf(s.y - m1) * iz1);
    pay_ex[2 * (size_t)(o0 + i) + 1] = __float_as_int(a);
  }
}

// ============================ aggregation kernels (32 lanes/row) ============================

// entity KG agg. HOP2: rscale_in multiply (and NO rscale_out write — R3 race).
// BF: src is a bf16x4-per-lane uint2 table (ent rows pre-offset); else fp32.
template <int HOP2, int BF>
__global__ __launch_bounds__(256) void entity_agg_kernel(
    const void* __restrict__ src, const int2* __restrict__ pay,
    const float* __restrict__ weight, const int* __restrict__ off,
    const float* __restrict__ rscale_in, float* __restrict__ Eout,
    float* __restrict__ rscale_out, float* __restrict__ res, int n) {
  int w = (int)((blockIdx.x * 256 + threadIdx.x) >> 5);
  int lane = threadIdx.x & 31;
  if (w >= n) return;
  int o0 = off[w], o1 = off[w + 1];
  float a0 = 0.f, a1 = 0.f, a2 = 0.f, a3 = 0.f;
#define EBODY(I)                                                            \
  {                                                                         \
    int2 pr = pay[I];                                                       \
    float rs = HOP2 ? rscale_in[pr.x] : 1.f;                                \
    float4 wv = ((const float4*)(weight + (size_t)pr.y * CH))[lane];        \
    float sx, sy, sz, sw;                                                   \
    if (BF) {                                                               \
      uint2 u = ((const uint2*)src)[(size_t)pr.x * 32 + lane];              \
      sx = bf16lo(u.x); sy = bf16hi(u.x); sz = bf16lo(u.y); sw = bf16hi(u.y); \
    } else {                                                                \
      float4 sv = ((const float4*)src)[(size_t)pr.x * 32 + lane];           \
      sx = sv.x; sy = sv.y; sz = sv.z; sw = sv.w;                           \
    }                                                                       \
    a0 += sx * wv.x * rs;                                                   \
    a1 += sy * wv.y * rs;                                                   \
    a2 += sz * wv.z * rs;                                                   \
    a3 += sw * wv.w * rs;                                                   \
  }
  int i = o0;
  for (; i + 4 <= o1; i += 4) { EBODY(i) EBODY(i + 1) EBODY(i + 2) EBODY(i + 3) }
  for (; i < o1; ++i) EBODY(i)
#undef EBODY
  int deg = o1 - o0;
  float inv = 1.f / (float)(deg > 0 ? deg : 1);
  a0 *= inv; a1 *= inv; a2 *= inv; a3 *= inv;
  float ss = a0 * a0 + a1 * a1 + a2 * a2 + a3 * a3;
#pragma unroll
  for (int d = 16; d; d >>= 1) ss += __shfl_xor(ss, d);
  float scale = 1.f / fmaxf(sqrtf(ss), 1e-12f);
  ((float4*)(Eout + (size_t)w * CH))[lane] = make_float4(a0, a1, a2, a3);
  if (!HOP2 && lane == 0) rscale_out[w] = scale;
  float4* rp = (float4*)(res + (size_t)w * CH);
  float4 r = rp[lane];
  r.x += a0 * scale; r.y += a1 * scale; r.z += a2 * scale; r.w += a3 * scale;
  rp[lane] = r;
}

// preference-graph agg; BF=1 → bf16 source table, BF=0 → fp32 user/ent
template <int BF>
__global__ __launch_bounds__(256) void node_agg_kernel(
    const void* __restrict__ srcU, const void* __restrict__ srcE,
    const int2* __restrict__ pay, const int* __restrict__ off,
    uint2* __restrict__ Nout, float* __restrict__ res, int n, int n_users,
    int write_norm) {
  int w = (int)((blockIdx.x * 256 + threadIdx.x) >> 5);
  int lane = threadIdx.x & 31;
  if (w >= n) return;
  int o0 = off[w], o1 = off[w + 1];
  float a0 = 0.f, a1 = 0.f, a2 = 0.f, a3 = 0.f;
#define NBODY(I)                                                          \
  {                                                                       \
    int2 pr = pay[I];                                                     \
    float aw = __int_as_float(pr.y);                                      \
    int tl = pr.x;                                                        \
    int r_ = (tl < n_users) ? tl : tl - n_users;                          \
    if (BF) {                                                             \
      const uint2* b = (const uint2*)((tl < n_users) ? srcU : srcE);      \
      uint2 u = b[(size_t)r_ * 32 + lane];                                \
      a0 += bf16lo(u.x) * aw;                                             \
      a1 += bf16hi(u.x) * aw;                                             \
      a2 += bf16lo(u.y) * aw;                                             \
      a3 += bf16hi(u.y) * aw;                                             \
    } else {                                                              \
      const float* b = (const float*)((tl < n_users) ? srcU : srcE);      \
      float4 sv = ((const float4*)(b + (size_t)r_ * CH))[lane];           \
      a0 += sv.x * aw; a1 += sv.y * aw; a2 += sv.z * aw; a3 += sv.w * aw; \
    }                                                                     \
  }
  int i = o0;
  for (; i + 4 <= o1; i += 4) { NBODY(i) NBODY(i + 1) NBODY(i + 2) NBODY(i + 3) }
  for (; i < o1; ++i) NBODY(i)
#undef NBODY
  int deg = o1 - o0;
  float inv = 1.f / (float)(deg > 0 ? deg : 1);
  a0 *= inv; a1 *= inv; a2 *= inv; a3 *= inv;
  float ss = a0 * a0 + a1 * a1 + a2 * a2 + a3 * a3;
#pragma unroll
  for (int d = 16; d; d >>= 1) ss += __shfl_xor(ss, d);
  float scale = 1.f / fmaxf(sqrtf(ss), 1e-12f);
  float n0 = a0 * scale, n1 = a1 * scale, n2 = a2 * scale, n3 = a3 * scale;
  if (write_norm)
    Nout[(size_t)w * 32 + lane] = make_uint2(bf16pack2(n0, n1), bf16pack2(n2, n3));
  float4* rp = (float4*)(res + (size_t)w * CH);
  float4 r = rp[lane];
  r.x += n0; r.y += n1; r.z += n2; r.w += n3;
  rp[lane] = r;
}

// user = segment_sum(val * Eun[col]); l2norm; accumulate residual
__global__ __launch_bounds__(256) void user_agg_kernel(const float* __restrict__ Eun,
                                                       const int2* __restrict__ pay,
                                                       const int* __restrict__ off,
                                                       float* __restrict__ res, int n) {
  int w = (int)((blockIdx.x * 256 + threadIdx.x) >> 5);
  int lane = threadIdx.x & 31;
  if (w >= n) return;
  int o0 = off[w], o1 = off[w + 1];
  float a0 = 0.f, a1 = 0.f, a2 = 0.f, a3 = 0.f;
#define UBODY(I)                                                    \
  {                                                                 \
    int2 pr = pay[I];                                               \
    float v = __int_as_float(pr.y);                                 \
    float4 sv = ((const float4*)(Eun + (size_t)pr.x * CH))[lane];   \
    a0 += sv.x * v; a1 += sv.y * v; a2 += sv.z * v; a3 += sv.w * v; \
  }
  int i = o0;
  for (; i + 4 <= o1; i += 4) { UBODY(i) UBODY(i + 1) UBODY(i + 2) UBODY(i + 3) }
  for (; i < o1; ++i) UBODY(i)
#undef UBODY
  float ss = a0 * a0 + a1 * a1 + a2 * a2 + a3 * a3;
#pragma unroll
  for (int d = 16; d; d >>= 1) ss += __shfl_xor(ss, d);
  float scale = 1.f / fmaxf(sqrtf(ss), 1e-12f);
  float4* rp = (float4*)(res + (size_t)w * CH);
  float4 r = rp[lane];
  r.x += a0 * scale; r.y += a1 * scale; r.z += a2 * scale; r.w += a3 * scale;
  rp[lane] = r;
}

// ============================ host ============================

extern "C" void kernel_launch(void* const* d_in, const int* in_sizes, int n_in,
                              void* d_out, int out_size, void* d_ws, size_t ws_size,
                              hipStream_t stream) {
  const float* user_emb = (const float*)d_in[0];
  const float* ent_emb  = (const float*)d_in[1];
  const int*   edge_index = (const int*)d_in[2];
  const int*   edge_type  = (const int*)d_in[3];
  const int*   ex_index   = (const int*)d_in[4];
  const int*   it_rows = (const int*)d_in[6];
  const int*   it_cols = (const int*)d_in[7];
  const float* it_vals = (const float*)d_in[8];
  const float* weight  = (const float*)d_in[9];
  const float* W_Q = (const float*)d_in[11];
  const float* W_K = (const float*)d_in[12];

  const int n_users = in_sizes[0] / CH;
  const int n_ents  = in_sizes[1] / CH;
  const int n_nodes = n_users + n_ents;
  const int n_kg    = in_sizes[3];
  const int n_ex    = in_sizes[5];
  const int nnz     = in_sizes[8];

  const int* kg_head = edge_index;
  const int* kg_tail = edge_index + n_kg;
  const int* ex_head = ex_index;
  const int* ex_tail = ex_index + n_ex;

  // ---- workspace bump allocator (256B aligned) ----
  char* p = (char*)d_ws;
  auto alloc = [&](size_t bytes) -> char* {
    char* r = p;
    p += (bytes + 255) & ~(size_t)255;
    return r;
  };
  int2* pay_kg = (int2*)alloc((size_t)n_kg * 8);
  int2* pay_ex = (int2*)alloc((size_t)n_ex * 8);
  size_t slotb = ((size_t)n_ex * 4 + 255) & ~(size_t)255;
  size_t unionA = slotb + (size_t)n_ex * 8;
  size_t unionB = (size_t)nnz * 8;
  char* uA = alloc(unionA > unionB ? unionA : unionB);
  int*    slot_ex = (int*)uA;
  float2* scores  = (float2*)(uA + slotb);
  int2*   pay_it  = (int2*)uA;
  char* cnt_base = alloc((size_t)(n_ents + n_nodes + n_users) * 4);
  int* cnt_kg = (int*)cnt_base;
  int* cnt_ex = cnt_kg + n_ents;
  int* cnt_it = cnt_ex + n_nodes;
  size_t cnt_bytes = (size_t)(n_ents + n_nodes + n_users) * 4;
  int* off_kg = (int*)alloc((size_t)(n_ents + 1) * 4);
  int* off_ex = (int*)alloc((size_t)(n_nodes + 1) * 4);
  int* off_it = (int*)alloc((size_t)(n_users + 1) * 4);
  int* bsum_kg = (int*)alloc(64 * 4);
  int* bsum_ex = (int*)alloc(64 * 4);
  int* bsum_it = (int*)alloc(64 * 4);
  unsigned short* WtQ = (unsigned short*)alloc((size_t)CH * CH * 2);
  unsigned short* WtK = (unsigned short*)alloc((size_t)CH * CH * 2);

  // arena region0: phase A = Qbf,Kbf (bf16); phase B = EunA,EunB,rscale,Nnbf.
  // optional Xnbf (bf16 concat embeddings) appended — written in phase A by qk_mfma,
  // read in phase B by hop-1 gathers. Gated on ws_size; fallback = fp32 paths.
  size_t sizeA = (size_t)2 * n_nodes * CH * 2;
  size_t sizeB = (size_t)2 * n_ents * CH * 4 + (((size_t)n_ents * 4 + 255) & ~(size_t)255) +
                 (size_t)n_nodes * CH * 2 + 512;
  size_t region0 = ((sizeA > sizeB ? sizeA : sizeB) + 255) & ~(size_t)255;
  size_t xbytes = (size_t)n_nodes * CH * 2;
  size_t used = (size_t)(p - (char*)d_ws);
  bool fitX = (used + region0 + xbytes + 4096) <= ws_size;
  char* arena = alloc(region0 + (fitX ? xbytes : 0));
  unsigned int* Qbf = (unsigned int*)arena;               // [n_nodes][64] uint
  unsigned int* Kbf = Qbf + (size_t)n_nodes * 64;
  float* EunA = (float*)arena;
  float* EunB = EunA + (size_t)n_ents * CH;
  float* rscaleE = EunB + (size_t)n_ents * CH;
  uint2* Nnbf = (uint2*)(((uintptr_t)(rscaleE + n_ents) + 255) & ~(uintptr_t)255);
  unsigned int* Xnbf = fitX ? (unsigned int*)(arena + region0) : nullptr;

  float* res_user = (float*)d_out;
  float* res_ent  = (float*)d_out + (size_t)n_users * CH;
  float* res_node = (float*)d_out + (size_t)n_nodes * CH;

  const int t_kg = (n_ents + SCAN_TILE - 1) / SCAN_TILE;
  const int t_ex = (n_nodes + SCAN_TILE - 1) / SCAN_TILE;
  const int t_it = (n_users + SCAN_TILE - 1) / SCAN_TILE;

  // ---- 1. CSR counts + hierarchical scans ----
  hipMemsetAsync(cnt_base, 0, cnt_bytes, stream);
  count_kernel<<<2048, 256, 0, stream>>>(kg_head, n_kg, cnt_kg);
  count_kernel<<<2048, 256, 0, stream>>>(ex_head, n_ex, cnt_ex);
  count_kernel<<<2048, 256, 0, stream>>>(it_rows, nnz, cnt_it);
  scan_sum_kernel<<<t_kg, 256, 0, stream>>>(cnt_kg, n_ents, bsum_kg);
  scan_sum_kernel<<<t_ex, 256, 0, stream>>>(cnt_ex, n_nodes, bsum_ex);
  scan_sum_kernel<<<t_it, 256, 0, stream>>>(cnt_it, n_users, bsum_it);
  scan_mid_kernel<<<1, 64, 0, stream>>>(bsum_kg, t_kg, off_kg, n_ents);
  scan_mid_kernel<<<1, 64, 0, stream>>>(bsum_ex, t_ex, off_ex, n_nodes);
  scan_mid_kernel<<<1, 64, 0, stream>>>(bsum_it, t_it, off_it, n_users);
  scan_apply_kernel<<<t_kg, 256, 0, stream>>>(cnt_kg, n_ents, bsum_kg, off_kg);
  scan_apply_kernel<<<t_ex, 256, 0, stream>>>(cnt_ex, n_nodes, bsum_ex, off_ex);
  scan_apply_kernel<<<t_it, 256, 0, stream>>>(cnt_it, n_users, bsum_it, off_it);
  hipMemsetAsync(cnt_base, 0, cnt_bytes, stream);
  fill_kg_kernel<<<2048, 256, 0, stream>>>(kg_head, kg_tail, edge_type, n_kg, off_kg,
                                           cnt_kg, pay_kg);
  fill_ex_kernel<<<2048, 256, 0, stream>>>(ex_head, ex_tail, n_ex, off_ex, cnt_ex,
                                           (int*)pay_ex, slot_ex);

  // ---- 2. residual init ----
  {
    int nu4 = n_users * (CH / 4), ne4 = n_ents * (CH / 4);
    int total = 2 * (nu4 + ne4);
    init_out_kernel<<<(total + 255) / 256, 256, 0, stream>>>(user_emb, ent_emb,
                                                             (float*)d_out, nu4, ne4);
  }

  // ---- 3. attention: MFMA Q/K projection + scores + softmax ----
  wtrans_kernel<<<(CH * CH + 255) / 256, 256, 0, stream>>>(W_Q, W_K, WtQ, WtK);
  qk_mfma_kernel<<<(n_nodes + 63) / 64, 256, 0, stream>>>(
      user_emb, ent_emb, WtQ, WtK, (unsigned short*)Qbf, (unsigned short*)Kbf, Xnbf,
      n_users, n_nodes);
  escore_kernel<<<(n_ex + 15) / 16, 256, 0, stream>>>((const uint4*)Qbf, (const uint4*)Kbf,
                                                      ex_head, ex_tail, slot_ex, scores,
                                                      n_ex);
  attn_kernel<<<(n_nodes + 3) / 4, 256, 0, stream>>>(off_ex, scores, (int*)pay_ex, n_nodes);

  // ---- 4. interact CSR fill ----
  fill_it_kernel<<<2048, 256, 0, stream>>>(it_rows, it_cols, it_vals, nnz, off_it, cnt_it,
                                           pay_it);

  // ---- 5. hop 1 ----
  if (Xnbf != nullptr) {
    entity_agg_kernel<0, 1><<<(n_ents + 7) / 8, 256, 0, stream>>>(
        (const uint2*)Xnbf + (size_t)n_users * 32, pay_kg, weight, off_kg, nullptr, EunA,
        rscaleE, res_ent, n_ents);
    node_agg_kernel<1><<<(n_nodes + 7) / 8, 256, 0, stream>>>(
        Xnbf, (const uint2*)Xnbf + (size_t)n_users * 32, pay_ex, off_ex, Nnbf, res_node,
        n_nodes, n_users, 1);
  } else {
    entity_agg_kernel<0, 0><<<(n_ents + 7) / 8, 256, 0, stream>>>(
        ent_emb, pay_kg, weight, off_kg, nullptr, EunA, rscaleE, res_ent, n_ents);
    node_agg_kernel<0><<<(n_nodes + 7) / 8, 256, 0, stream>>>(
        user_emb, ent_emb, pay_ex, off_ex, Nnbf, res_node, n_nodes, n_users, 1);
  }
  user_agg_kernel<<<(n_users + 7) / 8, 256, 0, stream>>>(EunA, pay_it, off_it, res_user,
                                                         n_users);

  // ---- 6. hop 2 ----
  entity_agg_kernel<1, 0><<<(n_ents + 7) / 8, 256, 0, stream>>>(
      EunA, pay_kg, weight, off_kg, rscaleE, EunB, nullptr, res_ent, n_ents);
  node_agg_kernel<1><<<(n_nodes + 7) / 8, 256, 0, stream>>>(
      Nnbf, Nnbf + (size_t)n_users * 32, pay_ex, off_ex, Nnbf, res_node, n_nodes,
      n_users, 0);
  user_agg_kernel<<<(n_users + 7) / 8, 256, 0, stream>>>(EunB, pay_it, off_it, res_user,
                                                         n_users);
}